// Round 11
// baseline (335.277 us; speedup 1.0000x reference)
//
#include <hip/hip_runtime.h>
#include <hip/hip_bf16.h>
#include <cstdint>
#include <cmath>

// MMoE forward, MI355X. B=16384 L=200 SD=64 CONCAT=244 NE=8 EH=256 EO=128 NT=2.
// R3: M-fold. R4: MFMA k4. R6: HW cvt. R7: MFMA k1. R8: swapped-MFMA k2.
// R10: 5 blocks/CU = L2 sweet spot. R11: register-held pooling (no re-gather;
// h-frags kept from L1, partials staged in freed sH1), vectorized k0 hist cvt.

typedef __attribute__((ext_vector_type(8))) short bfrag;   // 8 x bf16 (A/B frag)
typedef __attribute__((ext_vector_type(4))) float f32x4;   // C/D frag

__device__ __forceinline__ unsigned short f2bf(float f) {
  __hip_bfloat16 h = __float2bfloat16(f);          // HW v_cvt on gfx950 (RNE)
  return __builtin_bit_cast(unsigned short, h);
}
__device__ __forceinline__ float bf2f(unsigned short b) {
  union { unsigned u; float f; } v; v.u = ((unsigned)b) << 16;
  return v.f;
}
__device__ __forceinline__ float bfLo(unsigned hv) {
  union { unsigned u; float f; } v; v.u = hv << 16;
  return v.f;
}
__device__ __forceinline__ float bfHi(unsigned hv) {
  union { unsigned u; float f; } v; v.u = hv & 0xffff0000u;
  return v.f;
}

#define SWZ(row, col) ((col) ^ (((row) & 7) << 3))   // element-unit XOR swizzle (16B units)

// ---------------- workspace layout (bytes) ----------------
static constexpr size_t WS_ATTNB = 0;                       // bf16 [64][128]  (n-major)
static constexpr size_t WS_AW2T  = WS_ATTNB + 16384;        // bf16 [16][64]
static constexpr size_t WS_A13   = WS_AW2T + 2048;          // (unused gap)
static constexpr size_t WS_EW1T  = WS_A13 + 16384;          // bf16 [8][256][256]
static constexpr size_t WS_EW2T  = WS_EW1T + 1048576;       // bf16 [8][128][256]
static constexpr size_t WS_HISTB = WS_EW2T + 524288;        // bf16 [100001][64]
static constexpr size_t WS_TGT   = WS_HISTB + 12800256;     // bf16 [B][64]
static constexpr size_t WS_TA    = WS_TGT + 2097152;        // f32  [B][64]
static constexpr size_t WS_SHP   = WS_TA + 4194304;         // bf16 [B][256]
static constexpr size_t WS_EO    = WS_SHP + 8388608;        // bf16 [B][8][128]
static constexpr size_t WS_GWB   = WS_EO + 33554432;        // bf16 [16][256]
static constexpr size_t WS_TW1B  = WS_GWB + 8192;           // bf16 [2][64][128]
static constexpr size_t WS_TW2B  = WS_TW1B + 32768;         // bf16 [2][32][64]
static constexpr size_t WS_WPB   = WS_TW2B + 8192;          // bf16 [64][64]  Wproj^T (n-major)
static constexpr size_t WS_WAB   = WS_WPB + 8192;           // bf16 [64][64]  (Wproj@A13)^T
// total = WS_WAB + 8192 = 62,707,712 bytes of d_ws

// ---------------- k0: fold/transpose/bf16-cast weights + hist table ----------------
__launch_bounds__(256)
__global__ void k0_prep(const float* __restrict__ aW1, const float* __restrict__ aW2,
                        const float* __restrict__ eW1, const float* __restrict__ eW2,
                        const float* __restrict__ hist_E,
                        const float* __restrict__ gW, const float* __restrict__ tW1,
                        const float* __restrict__ tW2, const float* __restrict__ Wproj,
                        unsigned short* __restrict__ attnBt, unsigned short* __restrict__ aW2t,
                        unsigned short* __restrict__ eW1t, unsigned short* __restrict__ eW2t,
                        unsigned short* __restrict__ hist_b,
                        unsigned short* __restrict__ gWb, unsigned short* __restrict__ tW1b,
                        unsigned short* __restrict__ tW2b,
                        unsigned short* __restrict__ Wpb, unsigned short* __restrict__ WAb) {
  int tid = blockIdx.x * blockDim.x + threadIdx.x;
  int nth = gridDim.x * blockDim.x;
  // attnBt[n][k]: k<64 -> A2-A3, k>=64 -> A4
  for (int i = tid; i < 64 * 128; i += nth) {
    int n = i >> 7, k = i & 127;
    float v = (k < 64) ? (aW1[(64 + k) * 64 + n] - aW1[(128 + k) * 64 + n])
                       : aW1[(128 + k) * 64 + n];
    attnBt[i] = f2bf(v);
  }
  // aW2t[n][k]
  for (int i = tid; i < 16 * 64; i += nth) {
    int n = i >> 6, k = i & 63;
    aW2t[i] = f2bf(aW2[k * 16 + n]);
  }
  // Wpb[n][k] = Wproj[k][n]
  for (int i = tid; i < 64 * 64; i += nth) {
    int n = i >> 6, k = i & 63;
    Wpb[i] = f2bf(Wproj[k * 64 + n]);
  }
  // WAb[n][k] = sum_j Wproj[k][j]*(A1+A3)[j][n]
  for (int i = tid; i < 64 * 64; i += nth) {
    int n = i >> 6, k = i & 63;
    float s = 0.f;
    for (int j = 0; j < 64; ++j)
      s += Wproj[k * 64 + j] * (aW1[j * 64 + n] + aW1[(128 + j) * 64 + n]);
    WAb[i] = f2bf(s);
  }
  // eW1t[e][n][k]
  for (int i = tid; i < 8 * 256 * 256; i += nth) {
    int e = i >> 16, n = (i >> 8) & 255, k = i & 255;
    eW1t[i] = (k < 244) ? f2bf(eW1[(e * 244 + k) * 256 + n]) : (unsigned short)0;
  }
  // eW2t[e][n][k]
  for (int i = tid; i < 8 * 128 * 256; i += nth) {
    int e = i >> 15, n = (i >> 8) & 127, k = i & 255;
    eW2t[i] = f2bf(eW2[(e * 256 + k) * 128 + n]);
  }
  // gWb[n][k]
  for (int i = tid; i < 16 * 256; i += nth) {
    int n = i >> 8, k = i & 255, t = n >> 3, e = n & 7;
    gWb[i] = (k < 244) ? f2bf(gW[(t * 244 + k) * 8 + e]) : (unsigned short)0;
  }
  // tW1b[t][n][k]
  for (int i = tid; i < 2 * 64 * 128; i += nth) {
    int t = i >> 13, n = (i >> 7) & 63, k = i & 127;
    tW1b[i] = f2bf(tW1[(t * 128 + k) * 64 + n]);
  }
  // tW2b[t][n][k]
  for (int i = tid; i < 2 * 32 * 64; i += nth) {
    int t = i >> 11, n = (i >> 6) & 31, k = i & 63;
    tW2b[i] = f2bf(tW2[(t * 64 + k) * 32 + n]);
  }
  // bf16 hist table, vectorized 8-wide (6,400,064 = 800,008 * 8 exactly)
  for (int i = tid; i < 800008; i += nth) {
    const float* src = hist_E + (size_t)i * 8;
    float4 a = *(const float4*)src;
    float4 c = *(const float4*)(src + 4);
    uint4 q;
    q.x = (unsigned)f2bf(a.x) | ((unsigned)f2bf(a.y) << 16);
    q.y = (unsigned)f2bf(a.z) | ((unsigned)f2bf(a.w) << 16);
    q.z = (unsigned)f2bf(c.x) | ((unsigned)f2bf(c.y) << 16);
    q.w = (unsigned)f2bf(c.z) | ((unsigned)f2bf(c.w) << 16);
    *(uint4*)(hist_b + (size_t)i * 8) = q;
  }
}

// ---------------- k1: t = i_emb@Wproj ; tA = i_emb@WA + ab1  (MFMA) ----------------
__launch_bounds__(256)
__global__ void k1_tgt(const int* __restrict__ item_id, const float* __restrict__ item_E,
                       const unsigned short* __restrict__ Wpb, const unsigned short* __restrict__ WAb,
                       const float* __restrict__ ab1,
                       unsigned short* __restrict__ tgt, float* __restrict__ tA) {
  int tid = threadIdx.x, w = tid >> 6, lane = tid & 63;
  int lr = lane & 15, g = lane >> 4;
  int b0 = blockIdx.x * 64 + w * 16;
  int iid = item_id[b0 + lr];
  bfrag ia[2];
#pragma unroll
  for (int kk = 0; kk < 2; ++kk) {
    const float* src = item_E + (size_t)iid * 64 + kk * 32 + g * 8;
    float4 x = *(const float4*)src;
    float4 y = *(const float4*)(src + 4);
    bfrag r;
    r[0] = (short)f2bf(x.x); r[1] = (short)f2bf(x.y);
    r[2] = (short)f2bf(x.z); r[3] = (short)f2bf(x.w);
    r[4] = (short)f2bf(y.x); r[5] = (short)f2bf(y.y);
    r[6] = (short)f2bf(y.z); r[7] = (short)f2bf(y.w);
    ia[kk] = r;
  }
  f32x4 at[4], aa[4];
#pragma unroll
  for (int i = 0; i < 4; ++i) { at[i] = (f32x4){0,0,0,0}; aa[i] = (f32x4){0,0,0,0}; }
#pragma unroll
  for (int kk = 0; kk < 2; ++kk)
#pragma unroll
    for (int nt = 0; nt < 4; ++nt) {
      bfrag wp = *(const bfrag*)(Wpb + (nt * 16 + lr) * 64 + kk * 32 + g * 8);
      at[nt] = __builtin_amdgcn_mfma_f32_16x16x32_bf16(ia[kk], wp, at[nt], 0, 0, 0);
      bfrag wa = *(const bfrag*)(WAb + (nt * 16 + lr) * 64 + kk * 32 + g * 8);
      aa[nt] = __builtin_amdgcn_mfma_f32_16x16x32_bf16(ia[kk], wa, aa[nt], 0, 0, 0);
    }
  // D: col n = nt*16+lr, row m = b0 + g*4 + r
#pragma unroll
  for (int nt = 0; nt < 4; ++nt) {
    int n = nt * 16 + lr;
    float b1 = ab1[n];
#pragma unroll
    for (int r = 0; r < 4; ++r) {
      int m = b0 + g * 4 + r;
      tgt[(size_t)m * 64 + n] = f2bf(at[nt][r]);
      tA[(size_t)m * 64 + n] = aa[nt][r] + b1;
    }
  }
}

// ---------------- k3a: assemble shared (cols 0..179, pad 244..255) ----------------
__launch_bounds__(256)
__global__ void k3a_assemble(const int* __restrict__ user_id, const int* __restrict__ item_id,
                             const int* __restrict__ item_cat, const int* __restrict__ item_dur,
                             const float* __restrict__ user_dense, const float* __restrict__ item_dense,
                             const float* __restrict__ user_E, const float* __restrict__ item_E,
                             const float* __restrict__ cat_E, const float* __restrict__ dur_E,
                             unsigned short* __restrict__ shared_p) {
  int tid = threadIdx.x, w = tid >> 6, lane = tid & 63;
  int b = blockIdx.x * 4 + w;
  unsigned short* row = shared_p + (size_t)b * 256;
  row[lane]      = f2bf(user_E[(size_t)user_id[b] * 64 + lane]);
  row[64 + lane] = f2bf(item_E[(size_t)item_id[b] * 64 + lane]);
  if (lane < 16) row[128 + lane] = f2bf(cat_E[item_cat[b] * 16 + lane]);
  if (lane < 8)  row[144 + lane] = f2bf(dur_E[item_dur[b] * 8 + lane]);
  if (lane < 25) row[152 + lane] = f2bf(user_dense[b * 25 + lane]);
  if (lane < 3)  row[177 + lane] = f2bf(item_dense[b * 3 + lane]);
  if (lane < 12) row[244 + lane] = 0;
}

// ---------------- k2: fused DIN attention (reg-held pooling, 5 blocks/CU) ----------
__launch_bounds__(256, 5)
__global__ void k2_attn(const int* __restrict__ hist_seq, const unsigned short* __restrict__ hist_b,
                        const unsigned short* __restrict__ tgt, const float* __restrict__ tA,
                        const unsigned short* __restrict__ attnBt_g, const unsigned short* __restrict__ aW2t_g,
                        const float* __restrict__ ab2, const float* __restrict__ aW3,
                        unsigned short* __restrict__ shared_p) {
  __shared__ unsigned short sH1[208 * 64];   // L1 out (swizzled); transiently M, then f32[256][17] partials
  __shared__ int   ids[208];
  __shared__ float tv[64], tAv[64];
  __shared__ float sSc[208];
  __shared__ float red[8];
  int b = blockIdx.x;
  int tid = threadIdx.x, w = tid >> 6, lane = tid & 63;
  int lr = lane & 15, g = lane >> 4;

  if (tid < 208) ids[tid] = (tid < 200) ? hist_seq[(size_t)b * 200 + tid] : 0;
  if (tid < 64) tv[tid] = bf2f(tgt[(size_t)b * 64 + tid]);
  else if (tid < 128) tAv[tid - 64] = tA[(size_t)b * 64 + (tid - 64)];

  // layer-2 A fragments (aW2t rows n2=lr) + per-lane ab2/aW3 (n2 = g*4+r)
  bfrag b2fr[2];
#pragma unroll
  for (int kk = 0; kk < 2; ++kk)
    b2fr[kk] = *(const bfrag*)(aW2t_g + lr * 64 + kk * 32 + g * 8);
  f32x4 ab2v4 = *(const f32x4*)(ab2 + g * 4);
  f32x4 aW3v4 = *(const f32x4*)(aW3 + g * 4);
  __syncthreads();   // tv ready

  // cooperative M[n][k] = A23[n][k] + t[k]*A4[n][k] into sH1[0:4096] (swizzled)
  {
    int n = tid >> 2, k0 = (tid & 3) * 16;
    const unsigned short* rowp = attnBt_g + n * 128;
    unsigned short a23[16], a4[16], mo[16];
    *(uint4*)(a23)     = *(const uint4*)(rowp + k0);
    *(uint4*)(a23 + 8) = *(const uint4*)(rowp + k0 + 8);
    *(uint4*)(a4)      = *(const uint4*)(rowp + 64 + k0);
    *(uint4*)(a4 + 8)  = *(const uint4*)(rowp + 64 + k0 + 8);
#pragma unroll
    for (int i = 0; i < 16; ++i)
      mo[i] = f2bf(bf2f(a23[i]) + tv[k0 + i] * bf2f(a4[i]));
    *(uint4*)(sH1 + n * 64 + SWZ(n, k0))     = *(uint4*)(mo);
    *(uint4*)(sH1 + n * 64 + SWZ(n, k0 + 8)) = *(uint4*)(mo + 8);
  }
  __syncthreads();   // M ready

  // hoist M A-fragments (rows n1 = nt*16+lr) into registers
  bfrag mfr[4][2];
#pragma unroll
  for (int nt = 0; nt < 4; ++nt)
#pragma unroll
    for (int kk = 0; kk < 2; ++kk) {
      int n = nt * 16 + lr;
      mfr[nt][kk] = *(const bfrag*)(sH1 + n * 64 + SWZ(n, kk * 32 + g * 8));
    }
  __syncthreads();   // all waves have M; sH1 free for L1 output

  // layer 1 (swapped): D'[n1][m] = M x h ; keep h-frags live for pooling
  bfrag h0s[4], h1s[4];
#pragma unroll
  for (int s = 0; s < 4; ++s) {
    int mt = w + 4 * s;
    if (mt < 13) {
      int m = mt * 16 + lr;
      const unsigned short* hrow = hist_b + (size_t)ids[m] * 64;
      h0s[s] = *(const bfrag*)(hrow + g * 8);
      h1s[s] = *(const bfrag*)(hrow + 32 + g * 8);
      f32x4 acc[4] = {{0,0,0,0},{0,0,0,0},{0,0,0,0},{0,0,0,0}};
#pragma unroll
      for (int nt = 0; nt < 4; ++nt) {
        acc[nt] = __builtin_amdgcn_mfma_f32_16x16x32_bf16(mfr[nt][0], h0s[s], acc[nt], 0, 0, 0);
        acc[nt] = __builtin_amdgcn_mfma_f32_16x16x32_bf16(mfr[nt][1], h1s[s], acc[nt], 0, 0, 0);
      }
#pragma unroll
      for (int nt = 0; nt < 4; ++nt) {
        f32x4 ta4 = *(const f32x4*)(tAv + nt * 16 + g * 4);
        unsigned lo = (unsigned)f2bf(fmaxf(acc[nt][0] + ta4[0], 0.f))
                    | ((unsigned)f2bf(fmaxf(acc[nt][1] + ta4[1], 0.f)) << 16);
        unsigned hi = (unsigned)f2bf(fmaxf(acc[nt][2] + ta4[2], 0.f))
                    | ((unsigned)f2bf(fmaxf(acc[nt][3] + ta4[3], 0.f)) << 16);
        uint2 pk; pk.x = lo; pk.y = hi;
        *(uint2*)(sH1 + m * 64 + SWZ(m, nt * 16 + g * 4)) = pk;
      }
    }
  }
  __syncthreads();

  // layer 2 (swapped): D2[n2][m] = W2^T x H1^T ; 2-shuffle score reduce
#pragma unroll
  for (int s = 0; s < 4; ++s) {
    int mt = w + 4 * s;
    if (mt < 13) {
      int m = mt * 16 + lr;
      f32x4 acc2 = {0.f, 0.f, 0.f, 0.f};
#pragma unroll
      for (int kk = 0; kk < 2; ++kk) {
        bfrag hb = *(const bfrag*)(sH1 + m * 64 + SWZ(m, kk * 32 + g * 8));
        acc2 = __builtin_amdgcn_mfma_f32_16x16x32_bf16(b2fr[kk], hb, acc2, 0, 0, 0);
      }
      float p = 0.f;
#pragma unroll
      for (int r = 0; r < 4; ++r)
        p += fmaxf(acc2[r] + ab2v4[r], 0.f) * aW3v4[r];
      p += __shfl_xor(p, 16);
      p += __shfl_xor(p, 32);
      if (lane < 16) sSc[m] = p;
    }
  }
  __syncthreads();

  // masked softmax
  bool valid = false; float sc0 = 0.f;
  if (tid < 200 && ids[tid] != 0) { valid = true; sc0 = sSc[tid]; }
  float v = valid ? sc0 : -3.0e38f;
#pragma unroll
  for (int d = 1; d < 64; d <<= 1) v = fmaxf(v, __shfl_xor(v, d));
  if (lane == 0) red[w] = v;
  __syncthreads();
  float mx = fmaxf(fmaxf(red[0], red[1]), fmaxf(red[2], red[3]));
  float p = valid ? __expf(sc0 - mx) : 0.f;
  float s = p;
#pragma unroll
  for (int d = 1; d < 64; d <<= 1) s += __shfl_xor(s, d);
  if (lane == 0) red[4 + w] = s;
  if (tid < 208) sSc[tid] = p;
  __syncthreads();   // sSc(p) ready; all sH1 reads done

  // pooled: accumulate from register-held h (no re-gather)
  {
    float pacc[16];
#pragma unroll
    for (int i = 0; i < 16; ++i) pacc[i] = 0.f;
#pragma unroll
    for (int s2 = 0; s2 < 4; ++s2) {
      int mt = w + 4 * s2;
      if (mt < 13) {
        float pm = sSc[mt * 16 + lr];
#pragma unroll
        for (int i = 0; i < 8; ++i) {
          pacc[i]     += pm * bf2f((unsigned short)h0s[s2][i]);
          pacc[8 + i] += pm * bf2f((unsigned short)h1s[s2][i]);
        }
      }
    }
    float* sf = (float*)sH1;   // f32[256][17], conflict-free stride
#pragma unroll
    for (int i = 0; i < 16; ++i) sf[tid * 17 + i] = pacc[i];
  }
  __syncthreads();
  if (tid < 64) {
    float denom = red[4] + red[5] + red[6] + red[7] + 1e-30f;
    const float* sf = (const float*)sH1;
    int d = tid, gg = (d & 31) >> 3, ii = (d & 7) + ((d >> 5) << 3);
    float tot = 0.f;
#pragma unroll
    for (int ww = 0; ww < 4; ++ww)
#pragma unroll
      for (int l2 = 0; l2 < 16; ++l2)
        tot += sf[(ww * 64 + gg * 16 + l2) * 17 + ii];
    shared_p[(size_t)b * 256 + 180 + tid] = f2bf(tot / denom);
  }
}

// ---------------- k3b: experts (64-row tile x one expert per block) ----------------
__launch_bounds__(256, 2)
__global__ void k3b_experts(const unsigned short* __restrict__ shared_p,
                            const unsigned short* __restrict__ eW1t, const unsigned short* __restrict__ eW2t,
                            const float* __restrict__ eb1, const float* __restrict__ eb2,
                            unsigned short* __restrict__ eo_ws) {
  __shared__ unsigned short sX[64 * 256];
  __shared__ unsigned short sW[256 * 64];
  int tid = threadIdx.x, w = tid >> 6, lane = tid & 63;
  int e = blockIdx.x & 7;
  int b0 = (blockIdx.x >> 3) * 64;
  int lr = lane & 15, g = lane >> 4;

  for (int j = tid; j < 2048; j += 256) {
    int r = j >> 5, ke = (j & 31) * 8;
    uint4 v = *(const uint4*)(shared_p + (size_t)(b0 + r) * 256 + ke);
    *(uint4*)(sX + r * 256 + SWZ(r, ke)) = v;
  }
  f32x4 acc[16];
#pragma unroll
  for (int i = 0; i < 16; ++i) acc[i] = (f32x4){0.f, 0.f, 0.f, 0.f};
  const unsigned short* w1 = eW1t + (size_t)e * 256 * 256;
  for (int c = 0; c < 4; ++c) {
    __syncthreads();
    for (int j = tid; j < 2048; j += 256) {
      int n = j >> 3, ke = (j & 7) * 8;
      uint4 v = *(const uint4*)(w1 + n * 256 + c * 64 + ke);
      *(uint4*)(sW + n * 64 + SWZ(n, ke)) = v;
    }
    __syncthreads();
    int m = w * 16 + lr;
#pragma unroll
    for (int kk = 0; kk < 2; ++kk) {
      int kabs = c * 64 + kk * 32 + g * 8;
      bfrag a = *(const bfrag*)(sX + m * 256 + SWZ(m, kabs));
      int kloc = kk * 32 + g * 8;
#pragma unroll
      for (int nt = 0; nt < 16; ++nt) {
        int n = nt * 16 + lr;
        bfrag bb = *(const bfrag*)(sW + n * 64 + SWZ(n, kloc));
        acc[nt] = __builtin_amdgcn_mfma_f32_16x16x32_bf16(a, bb, acc[nt], 0, 0, 0);
      }
    }
  }
  __syncthreads();
#pragma unroll
  for (int nt = 0; nt < 16; ++nt) {
    int n = nt * 16 + lr;
    float bb = eb1[e * 256 + n];
#pragma unroll
    for (int r = 0; r < 4; ++r) {
      float vv = fmaxf(acc[nt][r] + bb, 0.f);
      int mm = w * 16 + g * 4 + r;
      sX[mm * 256 + SWZ(mm, n)] = f2bf(vv);
    }
  }
  f32x4 acc2[8];
#pragma unroll
  for (int i = 0; i < 8; ++i) acc2[i] = (f32x4){0.f, 0.f, 0.f, 0.f};
  const unsigned short* w2 = eW2t + (size_t)e * 128 * 256;
  for (int c = 0; c < 4; ++c) {
    __syncthreads();
    for (int j = tid; j < 1024; j += 256) {
      int n = j >> 3, ke = (j & 7) * 8;
      uint4 v = *(const uint4*)(w2 + n * 256 + c * 64 + ke);
      *(uint4*)(sW + n * 64 + SWZ(n, ke)) = v;
    }
    __syncthreads();
    int m = w * 16 + lr;
#pragma unroll
    for (int kk = 0; kk < 2; ++kk) {
      int kabs = c * 64 + kk * 32 + g * 8;
      bfrag a = *(const bfrag*)(sX + m * 256 + SWZ(m, kabs));
      int kloc = kk * 32 + g * 8;
#pragma unroll
      for (int nt = 0; nt < 8; ++nt) {
        int n = nt * 16 + lr;
        bfrag bb = *(const bfrag*)(sW + n * 64 + SWZ(n, kloc));
        acc2[nt] = __builtin_amdgcn_mfma_f32_16x16x32_bf16(a, bb, acc2[nt], 0, 0, 0);
      }
    }
  }
#pragma unroll
  for (int nt = 0; nt < 8; ++nt) {
    int n = nt * 16 + lr;
    float bb = eb2[e * 128 + n];
#pragma unroll
    for (int r = 0; r < 4; ++r) {
      float vv = fmaxf(acc2[nt][r] + bb, 0.f);
      int mm = w * 16 + g * 4 + r;
      eo_ws[((size_t)(b0 + mm) * 8 + e) * 128 + n] = f2bf(vv);
    }
  }
}

// ---------------- k4: gates + mixture + towers + sigmoid (MFMA tail) ----------------
__launch_bounds__(256, 3)
__global__ void k4_tail(const unsigned short* __restrict__ shared_p, const unsigned short* __restrict__ eo_ws,
                        const unsigned short* __restrict__ gWb, const float* __restrict__ gb,
                        const unsigned short* __restrict__ tW1b, const float* __restrict__ tb1,
                        const unsigned short* __restrict__ tW2b, const float* __restrict__ tb2,
                        const float* __restrict__ tW3, const float* __restrict__ tb3,
                        float* __restrict__ out) {
  __shared__ float sGL[32 * 17];
  __shared__ unsigned short sTi[2 * 32 * 128];
  __shared__ unsigned short sX1[2 * 32 * 64];
  int tid = threadIdx.x, w = tid >> 6, lane = tid & 63;
  int lr = lane & 15, g = lane >> 4;
  int b0 = blockIdx.x * 32;

  if (w < 2) {
    int m = b0 + w * 16 + lr;
    f32x4 acc = {0.f, 0.f, 0.f, 0.f};
#pragma unroll
    for (int kk = 0; kk < 8; ++kk) {
      bfrag a = *(const bfrag*)(shared_p + (size_t)m * 256 + kk * 32 + g * 8);
      bfrag bb = *(const bfrag*)(gWb + lr * 256 + kk * 32 + g * 8);
      acc = __builtin_amdgcn_mfma_f32_16x16x32_bf16(a, bb, acc, 0, 0, 0);
    }
    float gbv = gb[lr];
#pragma unroll
    for (int r = 0; r < 4; ++r)
      sGL[(w * 16 + g * 4 + r) * 17 + lr] = acc[r] + gbv;
  }
  __syncthreads();

  if (tid < 64) {
    int row = tid >> 1, t = tid & 1;
    float* p = sGL + row * 17 + t * 8;
    float mx = -3e38f;
#pragma unroll
    for (int e = 0; e < 8; ++e) mx = fmaxf(mx, p[e]);
    float sum = 0.f; float pe[8];
#pragma unroll
    for (int e = 0; e < 8; ++e) { pe[e] = __expf(p[e] - mx); sum += pe[e]; }
    float inv = 1.f / sum;
#pragma unroll
    for (int e = 0; e < 8; ++e) p[e] = pe[e] * inv;
  }
  __syncthreads();

  {
    int row = tid >> 3, q = tid & 7, t = q >> 2, o0 = (q & 3) * 32;
    const float* gp = sGL + row * 17 + t * 8;
    float accL[16], accH[16];
#pragma unroll
    for (int j = 0; j < 16; ++j) { accL[j] = 0.f; accH[j] = 0.f; }
    const unsigned short* base = eo_ws + ((size_t)(b0 + row) * 8) * 128 + o0;
#pragma unroll
    for (int e = 0; e < 8; ++e) {
      float ge = gp[e];
      const unsigned short* p = base + e * 128;
#pragma unroll
      for (int c = 0; c < 4; ++c) {
        uint4 v = *(const uint4*)(p + c * 8);
        const unsigned* u = (const unsigned*)&v;
#pragma unroll
        for (int j = 0; j < 4; ++j) {
          accL[c * 4 + j] += ge * bfLo(u[j]);
          accH[c * 4 + j] += ge * bfHi(u[j]);
        }
      }
    }
    unsigned short ob[32];
#pragma unroll
    for (int j = 0; j < 16; ++j) {
      ob[2 * j]     = f2bf(accL[j]);
      ob[2 * j + 1] = f2bf(accH[j]);
    }
#pragma unroll
    for (int c = 0; c < 4; ++c)
      *(uint4*)(sTi + t * 4096 + row * 128 + SWZ(row, o0 + c * 8)) = *(const uint4*)(ob + c * 8);
  }
  __syncthreads();

  int t = w >> 1, mt = w & 1;
  {
    f32x4 acc[4] = {{0.f,0.f,0.f,0.f},{0.f,0.f,0.f,0.f},{0.f,0.f,0.f,0.f},{0.f,0.f,0.f,0.f}};
    int ml = mt * 16 + lr;
#pragma unroll
    for (int kk = 0; kk < 4; ++kk) {
      bfrag a = *(const bfrag*)(sTi + t * 4096 + ml * 128 + SWZ(ml, kk * 32 + g * 8));
#pragma unroll
      for (int nt = 0; nt < 4; ++nt) {
        bfrag bb = *(const bfrag*)(tW1b + t * 8192 + (nt * 16 + lr) * 128 + kk * 32 + g * 8);
        acc[nt] = __builtin_amdgcn_mfma_f32_16x16x32_bf16(a, bb, acc[nt], 0, 0, 0);
      }
    }
#pragma unroll
    for (int nt = 0; nt < 4; ++nt) {
      int n = nt * 16 + lr;
      float bias = tb1[t * 64 + n];
#pragma unroll
      for (int r = 0; r < 4; ++r) {
        float x = fmaxf(acc[nt][r] + bias, 0.f);
        int row = mt * 16 + g * 4 + r;
        sX1[t * 2048 + row * 64 + SWZ(row, n)] = f2bf(x);
      }
    }
  }
  __syncthreads();

  {
    f32x4 acc[2] = {{0.f,0.f,0.f,0.f},{0.f,0.f,0.f,0.f}};
    int ml = mt * 16 + lr;
#pragma unroll
    for (int kk = 0; kk < 2; ++kk) {
      bfrag a = *(const bfrag*)(sX1 + t * 2048 + ml * 64 + SWZ(ml, kk * 32 + g * 8));
#pragma unroll
      for (int nt = 0; nt < 2; ++nt) {
        bfrag bb = *(const bfrag*)(tW2b + t * 2048 + (nt * 16 + lr) * 64 + kk * 32 + g * 8);
        acc[nt] = __builtin_amdgcn_mfma_f32_16x16x32_bf16(a, bb, acc[nt], 0, 0, 0);
      }
    }
    float part[4] = {0.f, 0.f, 0.f, 0.f};
#pragma unroll
    for (int nt = 0; nt < 2; ++nt) {
      int n = nt * 16 + lr;
      float bias = tb2[t * 32 + n];
      float w3 = tW3[t * 32 + n];
#pragma unroll
      for (int r = 0; r < 4; ++r)
        part[r] += fmaxf(acc[nt][r] + bias, 0.f) * w3;
    }
#pragma unroll
    for (int d = 1; d < 16; d <<= 1)
#pragma unroll
      for (int r = 0; r < 4; ++r) part[r] += __shfl_xor(part[r], d);
    if (lr == 0) {
      float b3 = tb3[t];
#pragma unroll
      for (int r = 0; r < 4; ++r) {
        float logit = part[r] + b3;
        out[(size_t)t * 16384 + b0 + mt * 16 + g * 4 + r] = 1.f / (1.f + __expf(-logit));
      }
    }
  }
}

// ---------------- launcher ----------------
extern "C" void kernel_launch(void* const* d_in, const int* in_sizes, int n_in,
                              void* d_out, int out_size, void* d_ws, size_t ws_size,
                              hipStream_t stream) {
  const int*   user_id    = (const int*)  d_in[0];
  const int*   item_id    = (const int*)  d_in[1];
  const int*   item_cat   = (const int*)  d_in[2];
  const int*   item_dur   = (const int*)  d_in[3];
  const float* user_dense = (const float*)d_in[4];
  const float* item_dense = (const float*)d_in[5];
  const int*   hist_seq   = (const int*)  d_in[6];
  const float* user_E     = (const float*)d_in[7];
  const float* item_E     = (const float*)d_in[8];
  const float* cat_E      = (const float*)d_in[9];
  const float* dur_E      = (const float*)d_in[10];
  const float* hist_E     = (const float*)d_in[11];
  const float* Wproj      = (const float*)d_in[12];
  const float* aW1        = (const float*)d_in[13];
  const float* ab1        = (const float*)d_in[14];
  const float* aW2        = (const float*)d_in[15];
  const float* ab2        = (const float*)d_in[16];
  const float* aW3        = (const float*)d_in[17];
  // d_in[18] = ab3: cancels in softmax, unused
  const float* eW1        = (const float*)d_in[19];
  const float* eb1        = (const float*)d_in[20];
  const float* eW2        = (const float*)d_in[21];
  const float* eb2        = (const float*)d_in[22];
  const float* gW         = (const float*)d_in[23];
  const float* gb         = (const float*)d_in[24];
  const float* tW1        = (const float*)d_in[25];
  const float* tb1        = (const float*)d_in[26];
  const float* tW2        = (const float*)d_in[27];
  const float* tb2        = (const float*)d_in[28];
  const float* tW3        = (const float*)d_in[29];
  const float* tb3        = (const float*)d_in[30];
  float* out = (float*)d_out;
  char* ws = (char*)d_ws;

  unsigned short* attnBt  = (unsigned short*)(ws + WS_ATTNB);
  unsigned short* aW2t    = (unsigned short*)(ws + WS_AW2T);
  unsigned short* eW1t    = (unsigned short*)(ws + WS_EW1T);
  unsigned short* eW2t    = (unsigned short*)(ws + WS_EW2T);
  unsigned short* hist_b  = (unsigned short*)(ws + WS_HISTB);
  unsigned short* tgt     = (unsigned short*)(ws + WS_TGT);
  float*          tA      = (float*)         (ws + WS_TA);
  unsigned short* shared_p= (unsigned short*)(ws + WS_SHP);
  unsigned short* eo_ws   = (unsigned short*)(ws + WS_EO);
  unsigned short* gWb     = (unsigned short*)(ws + WS_GWB);
  unsigned short* tW1b    = (unsigned short*)(ws + WS_TW1B);
  unsigned short* tW2b    = (unsigned short*)(ws + WS_TW2B);
  unsigned short* Wpb     = (unsigned short*)(ws + WS_WPB);
  unsigned short* WAb     = (unsigned short*)(ws + WS_WAB);

  k0_prep<<<2048, 256, 0, stream>>>(aW1, aW2, eW1, eW2, hist_E, gW, tW1, tW2, Wproj,
                                    attnBt, aW2t, eW1t, eW2t, hist_b,
                                    gWb, tW1b, tW2b, Wpb, WAb);
  k1_tgt<<<256, 256, 0, stream>>>(item_id, item_E, Wpb, WAb, ab1, tgt, tA);
  k3a_assemble<<<4096, 256, 0, stream>>>(user_id, item_id, item_cat, item_dur,
                                         user_dense, item_dense, user_E, item_E,
                                         cat_E, dur_E, shared_p);
  k2_attn<<<16384, 256, 0, stream>>>(hist_seq, hist_b, tgt, tA, attnBt, aW2t,
                                     ab2, aW3, shared_p);
  k3b_experts<<<2048, 256, 0, stream>>>(shared_p, eW1t, eW2t, eb1, eb2, eo_ws);
  k4_tail<<<512, 256, 0, stream>>>(shared_p, eo_ws, gWb, gb, tW1b, tb1, tW2b, tb2,
                                   tW3, tb3, out);
}

// Round 12
// 243.209 us; speedup vs baseline: 1.3786x; 1.3786x over previous
//
#include <hip/hip_runtime.h>
#include <hip/hip_bf16.h>
#include <cstdint>
#include <cmath>

// MMoE forward, MI355X. B=16384 L=200 SD=64 CONCAT=244 NE=8 EH=256 EO=128 NT=2.
// R3: M-fold. R4: MFMA k4. R6: HW cvt. R7: MFMA k1. R8: swapped-MFMA k2.
// R10: 5 blocks/CU = L2 sweet spot (k2=147us baseline). R11 lesson: guarded
// per-lane arrays spill to scratch (VGPR stays 48, WRITE balloons) -> reverted.
// R12: k2 == R10 verbatim; keep R11's vectorized k0 hist conversion only.

typedef __attribute__((ext_vector_type(8))) short bfrag;   // 8 x bf16 (A/B frag)
typedef __attribute__((ext_vector_type(4))) float f32x4;   // C/D frag

__device__ __forceinline__ unsigned short f2bf(float f) {
  __hip_bfloat16 h = __float2bfloat16(f);          // HW v_cvt on gfx950 (RNE)
  return __builtin_bit_cast(unsigned short, h);
}
__device__ __forceinline__ float bf2f(unsigned short b) {
  union { unsigned u; float f; } v; v.u = ((unsigned)b) << 16;
  return v.f;
}
__device__ __forceinline__ float bfLo(unsigned hv) {
  union { unsigned u; float f; } v; v.u = hv << 16;
  return v.f;
}
__device__ __forceinline__ float bfHi(unsigned hv) {
  union { unsigned u; float f; } v; v.u = hv & 0xffff0000u;
  return v.f;
}

#define SWZ(row, col) ((col) ^ (((row) & 7) << 3))   // element-unit XOR swizzle (16B units)

// ---------------- workspace layout (bytes) ----------------
static constexpr size_t WS_ATTNB = 0;                       // bf16 [64][128]  (n-major)
static constexpr size_t WS_AW2T  = WS_ATTNB + 16384;        // bf16 [16][64]
static constexpr size_t WS_A13   = WS_AW2T + 2048;          // (unused gap)
static constexpr size_t WS_EW1T  = WS_A13 + 16384;          // bf16 [8][256][256]
static constexpr size_t WS_EW2T  = WS_EW1T + 1048576;       // bf16 [8][128][256]
static constexpr size_t WS_HISTB = WS_EW2T + 524288;        // bf16 [100001][64]
static constexpr size_t WS_TGT   = WS_HISTB + 12800256;     // bf16 [B][64]
static constexpr size_t WS_TA    = WS_TGT + 2097152;        // f32  [B][64]
static constexpr size_t WS_SHP   = WS_TA + 4194304;         // bf16 [B][256]
static constexpr size_t WS_EO    = WS_SHP + 8388608;        // bf16 [B][8][128]
static constexpr size_t WS_GWB   = WS_EO + 33554432;        // bf16 [16][256]
static constexpr size_t WS_TW1B  = WS_GWB + 8192;           // bf16 [2][64][128]
static constexpr size_t WS_TW2B  = WS_TW1B + 32768;         // bf16 [2][32][64]
static constexpr size_t WS_WPB   = WS_TW2B + 8192;          // bf16 [64][64]  Wproj^T (n-major)
static constexpr size_t WS_WAB   = WS_WPB + 8192;           // bf16 [64][64]  (Wproj@A13)^T
// total = WS_WAB + 8192 = 62,707,712 bytes of d_ws

// ---------------- k0: fold/transpose/bf16-cast weights + hist table ----------------
__launch_bounds__(256)
__global__ void k0_prep(const float* __restrict__ aW1, const float* __restrict__ aW2,
                        const float* __restrict__ eW1, const float* __restrict__ eW2,
                        const float* __restrict__ hist_E,
                        const float* __restrict__ gW, const float* __restrict__ tW1,
                        const float* __restrict__ tW2, const float* __restrict__ Wproj,
                        unsigned short* __restrict__ attnBt, unsigned short* __restrict__ aW2t,
                        unsigned short* __restrict__ eW1t, unsigned short* __restrict__ eW2t,
                        unsigned short* __restrict__ hist_b,
                        unsigned short* __restrict__ gWb, unsigned short* __restrict__ tW1b,
                        unsigned short* __restrict__ tW2b,
                        unsigned short* __restrict__ Wpb, unsigned short* __restrict__ WAb) {
  int tid = blockIdx.x * blockDim.x + threadIdx.x;
  int nth = gridDim.x * blockDim.x;
  // attnBt[n][k]: k<64 -> A2-A3, k>=64 -> A4
  for (int i = tid; i < 64 * 128; i += nth) {
    int n = i >> 7, k = i & 127;
    float v = (k < 64) ? (aW1[(64 + k) * 64 + n] - aW1[(128 + k) * 64 + n])
                       : aW1[(128 + k) * 64 + n];
    attnBt[i] = f2bf(v);
  }
  // aW2t[n][k]
  for (int i = tid; i < 16 * 64; i += nth) {
    int n = i >> 6, k = i & 63;
    aW2t[i] = f2bf(aW2[k * 16 + n]);
  }
  // Wpb[n][k] = Wproj[k][n]
  for (int i = tid; i < 64 * 64; i += nth) {
    int n = i >> 6, k = i & 63;
    Wpb[i] = f2bf(Wproj[k * 64 + n]);
  }
  // WAb[n][k] = sum_j Wproj[k][j]*(A1+A3)[j][n]
  for (int i = tid; i < 64 * 64; i += nth) {
    int n = i >> 6, k = i & 63;
    float s = 0.f;
    for (int j = 0; j < 64; ++j)
      s += Wproj[k * 64 + j] * (aW1[j * 64 + n] + aW1[(128 + j) * 64 + n]);
    WAb[i] = f2bf(s);
  }
  // eW1t[e][n][k]
  for (int i = tid; i < 8 * 256 * 256; i += nth) {
    int e = i >> 16, n = (i >> 8) & 255, k = i & 255;
    eW1t[i] = (k < 244) ? f2bf(eW1[(e * 244 + k) * 256 + n]) : (unsigned short)0;
  }
  // eW2t[e][n][k]
  for (int i = tid; i < 8 * 128 * 256; i += nth) {
    int e = i >> 15, n = (i >> 8) & 127, k = i & 255;
    eW2t[i] = f2bf(eW2[(e * 256 + k) * 128 + n]);
  }
  // gWb[n][k]
  for (int i = tid; i < 16 * 256; i += nth) {
    int n = i >> 8, k = i & 255, t = n >> 3, e = n & 7;
    gWb[i] = (k < 244) ? f2bf(gW[(t * 244 + k) * 8 + e]) : (unsigned short)0;
  }
  // tW1b[t][n][k]
  for (int i = tid; i < 2 * 64 * 128; i += nth) {
    int t = i >> 13, n = (i >> 7) & 63, k = i & 127;
    tW1b[i] = f2bf(tW1[(t * 128 + k) * 64 + n]);
  }
  // tW2b[t][n][k]
  for (int i = tid; i < 2 * 32 * 64; i += nth) {
    int t = i >> 11, n = (i >> 6) & 31, k = i & 63;
    tW2b[i] = f2bf(tW2[(t * 64 + k) * 32 + n]);
  }
  // bf16 hist table, vectorized 8-wide (6,400,064 = 800,008 * 8 exactly)
  for (int i = tid; i < 800008; i += nth) {
    const float* src = hist_E + (size_t)i * 8;
    float4 a = *(const float4*)src;
    float4 c = *(const float4*)(src + 4);
    uint4 q;
    q.x = (unsigned)f2bf(a.x) | ((unsigned)f2bf(a.y) << 16);
    q.y = (unsigned)f2bf(a.z) | ((unsigned)f2bf(a.w) << 16);
    q.z = (unsigned)f2bf(c.x) | ((unsigned)f2bf(c.y) << 16);
    q.w = (unsigned)f2bf(c.z) | ((unsigned)f2bf(c.w) << 16);
    *(uint4*)(hist_b + (size_t)i * 8) = q;
  }
}

// ---------------- k1: t = i_emb@Wproj ; tA = i_emb@WA + ab1  (MFMA) ----------------
__launch_bounds__(256)
__global__ void k1_tgt(const int* __restrict__ item_id, const float* __restrict__ item_E,
                       const unsigned short* __restrict__ Wpb, const unsigned short* __restrict__ WAb,
                       const float* __restrict__ ab1,
                       unsigned short* __restrict__ tgt, float* __restrict__ tA) {
  int tid = threadIdx.x, w = tid >> 6, lane = tid & 63;
  int lr = lane & 15, g = lane >> 4;
  int b0 = blockIdx.x * 64 + w * 16;
  int iid = item_id[b0 + lr];
  bfrag ia[2];
#pragma unroll
  for (int kk = 0; kk < 2; ++kk) {
    const float* src = item_E + (size_t)iid * 64 + kk * 32 + g * 8;
    float4 x = *(const float4*)src;
    float4 y = *(const float4*)(src + 4);
    bfrag r;
    r[0] = (short)f2bf(x.x); r[1] = (short)f2bf(x.y);
    r[2] = (short)f2bf(x.z); r[3] = (short)f2bf(x.w);
    r[4] = (short)f2bf(y.x); r[5] = (short)f2bf(y.y);
    r[6] = (short)f2bf(y.z); r[7] = (short)f2bf(y.w);
    ia[kk] = r;
  }
  f32x4 at[4], aa[4];
#pragma unroll
  for (int i = 0; i < 4; ++i) { at[i] = (f32x4){0,0,0,0}; aa[i] = (f32x4){0,0,0,0}; }
#pragma unroll
  for (int kk = 0; kk < 2; ++kk)
#pragma unroll
    for (int nt = 0; nt < 4; ++nt) {
      bfrag wp = *(const bfrag*)(Wpb + (nt * 16 + lr) * 64 + kk * 32 + g * 8);
      at[nt] = __builtin_amdgcn_mfma_f32_16x16x32_bf16(ia[kk], wp, at[nt], 0, 0, 0);
      bfrag wa = *(const bfrag*)(WAb + (nt * 16 + lr) * 64 + kk * 32 + g * 8);
      aa[nt] = __builtin_amdgcn_mfma_f32_16x16x32_bf16(ia[kk], wa, aa[nt], 0, 0, 0);
    }
  // D: col n = nt*16+lr, row m = b0 + g*4 + r
#pragma unroll
  for (int nt = 0; nt < 4; ++nt) {
    int n = nt * 16 + lr;
    float b1 = ab1[n];
#pragma unroll
    for (int r = 0; r < 4; ++r) {
      int m = b0 + g * 4 + r;
      tgt[(size_t)m * 64 + n] = f2bf(at[nt][r]);
      tA[(size_t)m * 64 + n] = aa[nt][r] + b1;
    }
  }
}

// ---------------- k3a: assemble shared (cols 0..179, pad 244..255) ----------------
__launch_bounds__(256)
__global__ void k3a_assemble(const int* __restrict__ user_id, const int* __restrict__ item_id,
                             const int* __restrict__ item_cat, const int* __restrict__ item_dur,
                             const float* __restrict__ user_dense, const float* __restrict__ item_dense,
                             const float* __restrict__ user_E, const float* __restrict__ item_E,
                             const float* __restrict__ cat_E, const float* __restrict__ dur_E,
                             unsigned short* __restrict__ shared_p) {
  int tid = threadIdx.x, w = tid >> 6, lane = tid & 63;
  int b = blockIdx.x * 4 + w;
  unsigned short* row = shared_p + (size_t)b * 256;
  row[lane]      = f2bf(user_E[(size_t)user_id[b] * 64 + lane]);
  row[64 + lane] = f2bf(item_E[(size_t)item_id[b] * 64 + lane]);
  if (lane < 16) row[128 + lane] = f2bf(cat_E[item_cat[b] * 16 + lane]);
  if (lane < 8)  row[144 + lane] = f2bf(dur_E[item_dur[b] * 8 + lane]);
  if (lane < 25) row[152 + lane] = f2bf(user_dense[b * 25 + lane]);
  if (lane < 3)  row[177 + lane] = f2bf(item_dense[b * 3 + lane]);
  if (lane < 12) row[244 + lane] = 0;
}

// ---------------- k2: fused DIN attention (single-pass swapped, 5 blocks/CU) -------
__launch_bounds__(256, 5)
__global__ void k2_attn(const int* __restrict__ hist_seq, const unsigned short* __restrict__ hist_b,
                        const unsigned short* __restrict__ tgt, const float* __restrict__ tA,
                        const unsigned short* __restrict__ attnBt_g, const unsigned short* __restrict__ aW2t_g,
                        const float* __restrict__ ab2, const float* __restrict__ aW3,
                        unsigned short* __restrict__ shared_p) {
  __shared__ unsigned short sH1[208 * 64];   // L1 out (swizzled); first 4096 transiently hold M
  __shared__ int   ids[208];
  __shared__ float tv[64], tAv[64];
  __shared__ float sSc[208];
  __shared__ float red[8];
  __shared__ float pbuf[512];
  int b = blockIdx.x;
  int tid = threadIdx.x, w = tid >> 6, lane = tid & 63;
  int lr = lane & 15, g = lane >> 4;

  if (tid < 208) ids[tid] = (tid < 200) ? hist_seq[(size_t)b * 200 + tid] : 0;
  if (tid < 64) tv[tid] = bf2f(tgt[(size_t)b * 64 + tid]);
  else if (tid < 128) tAv[tid - 64] = tA[(size_t)b * 64 + (tid - 64)];

  // layer-2 A fragments (aW2t rows n2=lr) + per-lane ab2/aW3 (n2 = g*4+r)
  bfrag b2fr[2];
#pragma unroll
  for (int kk = 0; kk < 2; ++kk)
    b2fr[kk] = *(const bfrag*)(aW2t_g + lr * 64 + kk * 32 + g * 8);
  f32x4 ab2v4 = *(const f32x4*)(ab2 + g * 4);
  f32x4 aW3v4 = *(const f32x4*)(aW3 + g * 4);
  __syncthreads();   // tv ready

  // cooperative M[n][k] = A23[n][k] + t[k]*A4[n][k] into sH1[0:4096] (swizzled)
  {
    int n = tid >> 2, k0 = (tid & 3) * 16;
    const unsigned short* rowp = attnBt_g + n * 128;
    unsigned short a23[16], a4[16], mo[16];
    *(uint4*)(a23)     = *(const uint4*)(rowp + k0);
    *(uint4*)(a23 + 8) = *(const uint4*)(rowp + k0 + 8);
    *(uint4*)(a4)      = *(const uint4*)(rowp + 64 + k0);
    *(uint4*)(a4 + 8)  = *(const uint4*)(rowp + 64 + k0 + 8);
#pragma unroll
    for (int i = 0; i < 16; ++i)
      mo[i] = f2bf(bf2f(a23[i]) + tv[k0 + i] * bf2f(a4[i]));
    *(uint4*)(sH1 + n * 64 + SWZ(n, k0))     = *(uint4*)(mo);
    *(uint4*)(sH1 + n * 64 + SWZ(n, k0 + 8)) = *(uint4*)(mo + 8);
  }
  __syncthreads();   // M ready

  // hoist M A-fragments (rows n1 = nt*16+lr) into registers
  bfrag mfr[4][2];
#pragma unroll
  for (int nt = 0; nt < 4; ++nt)
#pragma unroll
    for (int kk = 0; kk < 2; ++kk) {
      int n = nt * 16 + lr;
      mfr[nt][kk] = *(const bfrag*)(sH1 + n * 64 + SWZ(n, kk * 32 + g * 8));
    }
  __syncthreads();   // all waves have M; sH1 free for L1 output

  // layer 1 (swapped): D'[n1][m] = M x h ; lane holds 4 consecutive n-cols of row m
  for (int mt = w; mt < 13; mt += 4) {
    int m = mt * 16 + lr;
    const unsigned short* hrow = hist_b + (size_t)ids[m] * 64;
    bfrag h0 = *(const bfrag*)(hrow + g * 8);
    bfrag h1 = *(const bfrag*)(hrow + 32 + g * 8);
    f32x4 acc[4] = {{0,0,0,0},{0,0,0,0},{0,0,0,0},{0,0,0,0}};
#pragma unroll
    for (int nt = 0; nt < 4; ++nt) {
      acc[nt] = __builtin_amdgcn_mfma_f32_16x16x32_bf16(mfr[nt][0], h0, acc[nt], 0, 0, 0);
      acc[nt] = __builtin_amdgcn_mfma_f32_16x16x32_bf16(mfr[nt][1], h1, acc[nt], 0, 0, 0);
    }
#pragma unroll
    for (int nt = 0; nt < 4; ++nt) {
      f32x4 ta4 = *(const f32x4*)(tAv + nt * 16 + g * 4);
      unsigned lo = (unsigned)f2bf(fmaxf(acc[nt][0] + ta4[0], 0.f))
                  | ((unsigned)f2bf(fmaxf(acc[nt][1] + ta4[1], 0.f)) << 16);
      unsigned hi = (unsigned)f2bf(fmaxf(acc[nt][2] + ta4[2], 0.f))
                  | ((unsigned)f2bf(fmaxf(acc[nt][3] + ta4[3], 0.f)) << 16);
      uint2 pk; pk.x = lo; pk.y = hi;
      *(uint2*)(sH1 + m * 64 + SWZ(m, nt * 16 + g * 4)) = pk;
    }
  }
  __syncthreads();

  // layer 2 (swapped): D2[n2][m] = W2^T x H1^T ; 2-shuffle score reduce
  for (int mt = w; mt < 13; mt += 4) {
    int m = mt * 16 + lr;
    f32x4 acc2 = {0.f, 0.f, 0.f, 0.f};
#pragma unroll
    for (int kk = 0; kk < 2; ++kk) {
      bfrag hb = *(const bfrag*)(sH1 + m * 64 + SWZ(m, kk * 32 + g * 8));
      acc2 = __builtin_amdgcn_mfma_f32_16x16x32_bf16(b2fr[kk], hb, acc2, 0, 0, 0);
    }
    float p = 0.f;
#pragma unroll
    for (int r = 0; r < 4; ++r)
      p += fmaxf(acc2[r] + ab2v4[r], 0.f) * aW3v4[r];
    p += __shfl_xor(p, 16);
    p += __shfl_xor(p, 32);
    if (lane < 16) sSc[m] = p;
  }
  __syncthreads();

  // masked softmax
  bool valid = false; float sc0 = 0.f;
  if (tid < 200 && ids[tid] != 0) { valid = true; sc0 = sSc[tid]; }
  float v = valid ? sc0 : -3.0e38f;
#pragma unroll
  for (int d = 1; d < 64; d <<= 1) v = fmaxf(v, __shfl_xor(v, d));
  if (lane == 0) red[w] = v;
  __syncthreads();
  float mx = fmaxf(fmaxf(red[0], red[1]), fmaxf(red[2], red[3]));
  float p = valid ? __expf(sc0 - mx) : 0.f;
  float s = p;
#pragma unroll
  for (int d = 1; d < 64; d <<= 1) s += __shfl_xor(s, d);
  if (lane == 0) red[4 + w] = s;
  if (tid < 208) sSc[tid] = p;
  __syncthreads();
  float denom = red[4] + red[5] + red[6] + red[7] + 1e-30f;

  // pooled: re-gather h (cache-warm) weighted by attn
  {
    int hp = lane >> 5, hl = lane & 31;
    float a0 = 0.f, a1 = 0.f;
    for (int i = 0; i < 25; ++i) {
      int l = w * 50 + hp * 25 + i;
      unsigned hv = *(const unsigned*)(hist_b + (size_t)ids[l] * 64 + 2 * hl);
      float pw = sSc[l];
      a0 += pw * bfLo(hv);
      a1 += pw * bfHi(hv);
    }
    pbuf[(w * 2 + hp) * 64 + 2 * hl]     = a0;
    pbuf[(w * 2 + hp) * 64 + 2 * hl + 1] = a1;
  }
  __syncthreads();
  if (tid < 64) {
    float tot = 0.f;
#pragma unroll
    for (int c = 0; c < 8; ++c) tot += pbuf[c * 64 + tid];
    shared_p[(size_t)b * 256 + 180 + tid] = f2bf(tot / denom);
  }
}

// ---------------- k3b: experts (64-row tile x one expert per block) ----------------
__launch_bounds__(256, 2)
__global__ void k3b_experts(const unsigned short* __restrict__ shared_p,
                            const unsigned short* __restrict__ eW1t, const unsigned short* __restrict__ eW2t,
                            const float* __restrict__ eb1, const float* __restrict__ eb2,
                            unsigned short* __restrict__ eo_ws) {
  __shared__ unsigned short sX[64 * 256];
  __shared__ unsigned short sW[256 * 64];
  int tid = threadIdx.x, w = tid >> 6, lane = tid & 63;
  int e = blockIdx.x & 7;
  int b0 = (blockIdx.x >> 3) * 64;
  int lr = lane & 15, g = lane >> 4;

  for (int j = tid; j < 2048; j += 256) {
    int r = j >> 5, ke = (j & 31) * 8;
    uint4 v = *(const uint4*)(shared_p + (size_t)(b0 + r) * 256 + ke);
    *(uint4*)(sX + r * 256 + SWZ(r, ke)) = v;
  }
  f32x4 acc[16];
#pragma unroll
  for (int i = 0; i < 16; ++i) acc[i] = (f32x4){0.f, 0.f, 0.f, 0.f};
  const unsigned short* w1 = eW1t + (size_t)e * 256 * 256;
  for (int c = 0; c < 4; ++c) {
    __syncthreads();
    for (int j = tid; j < 2048; j += 256) {
      int n = j >> 3, ke = (j & 7) * 8;
      uint4 v = *(const uint4*)(w1 + n * 256 + c * 64 + ke);
      *(uint4*)(sW + n * 64 + SWZ(n, ke)) = v;
    }
    __syncthreads();
    int m = w * 16 + lr;
#pragma unroll
    for (int kk = 0; kk < 2; ++kk) {
      int kabs = c * 64 + kk * 32 + g * 8;
      bfrag a = *(const bfrag*)(sX + m * 256 + SWZ(m, kabs));
      int kloc = kk * 32 + g * 8;
#pragma unroll
      for (int nt = 0; nt < 16; ++nt) {
        int n = nt * 16 + lr;
        bfrag bb = *(const bfrag*)(sW + n * 64 + SWZ(n, kloc));
        acc[nt] = __builtin_amdgcn_mfma_f32_16x16x32_bf16(a, bb, acc[nt], 0, 0, 0);
      }
    }
  }
  __syncthreads();
#pragma unroll
  for (int nt = 0; nt < 16; ++nt) {
    int n = nt * 16 + lr;
    float bb = eb1[e * 256 + n];
#pragma unroll
    for (int r = 0; r < 4; ++r) {
      float vv = fmaxf(acc[nt][r] + bb, 0.f);
      int mm = w * 16 + g * 4 + r;
      sX[mm * 256 + SWZ(mm, n)] = f2bf(vv);
    }
  }
  f32x4 acc2[8];
#pragma unroll
  for (int i = 0; i < 8; ++i) acc2[i] = (f32x4){0.f, 0.f, 0.f, 0.f};
  const unsigned short* w2 = eW2t + (size_t)e * 128 * 256;
  for (int c = 0; c < 4; ++c) {
    __syncthreads();
    for (int j = tid; j < 1024; j += 256) {
      int n = j >> 3, ke = (j & 7) * 8;
      uint4 v = *(const uint4*)(w2 + n * 256 + c * 64 + ke);
      *(uint4*)(sW + n * 64 + SWZ(n, ke)) = v;
    }
    __syncthreads();
    int m = w * 16 + lr;
#pragma unroll
    for (int kk = 0; kk < 2; ++kk) {
      int kabs = c * 64 + kk * 32 + g * 8;
      bfrag a = *(const bfrag*)(sX + m * 256 + SWZ(m, kabs));
      int kloc = kk * 32 + g * 8;
#pragma unroll
      for (int nt = 0; nt < 8; ++nt) {
        int n = nt * 16 + lr;
        bfrag bb = *(const bfrag*)(sW + n * 64 + SWZ(n, kloc));
        acc2[nt] = __builtin_amdgcn_mfma_f32_16x16x32_bf16(a, bb, acc2[nt], 0, 0, 0);
      }
    }
  }
#pragma unroll
  for (int nt = 0; nt < 8; ++nt) {
    int n = nt * 16 + lr;
    float bb = eb2[e * 128 + n];
#pragma unroll
    for (int r = 0; r < 4; ++r) {
      float vv = fmaxf(acc2[nt][r] + bb, 0.f);
      int mm = w * 16 + g * 4 + r;
      eo_ws[((size_t)(b0 + mm) * 8 + e) * 128 + n] = f2bf(vv);
    }
  }
}

// ---------------- k4: gates + mixture + towers + sigmoid (MFMA tail) ----------------
__launch_bounds__(256, 3)
__global__ void k4_tail(const unsigned short* __restrict__ shared_p, const unsigned short* __restrict__ eo_ws,
                        const unsigned short* __restrict__ gWb, const float* __restrict__ gb,
                        const unsigned short* __restrict__ tW1b, const float* __restrict__ tb1,
                        const unsigned short* __restrict__ tW2b, const float* __restrict__ tb2,
                        const float* __restrict__ tW3, const float* __restrict__ tb3,
                        float* __restrict__ out) {
  __shared__ float sGL[32 * 17];
  __shared__ unsigned short sTi[2 * 32 * 128];
  __shared__ unsigned short sX1[2 * 32 * 64];
  int tid = threadIdx.x, w = tid >> 6, lane = tid & 63;
  int lr = lane & 15, g = lane >> 4;
  int b0 = blockIdx.x * 32;

  if (w < 2) {
    int m = b0 + w * 16 + lr;
    f32x4 acc = {0.f, 0.f, 0.f, 0.f};
#pragma unroll
    for (int kk = 0; kk < 8; ++kk) {
      bfrag a = *(const bfrag*)(shared_p + (size_t)m * 256 + kk * 32 + g * 8);
      bfrag bb = *(const bfrag*)(gWb + lr * 256 + kk * 32 + g * 8);
      acc = __builtin_amdgcn_mfma_f32_16x16x32_bf16(a, bb, acc, 0, 0, 0);
    }
    float gbv = gb[lr];
#pragma unroll
    for (int r = 0; r < 4; ++r)
      sGL[(w * 16 + g * 4 + r) * 17 + lr] = acc[r] + gbv;
  }
  __syncthreads();

  if (tid < 64) {
    int row = tid >> 1, t = tid & 1;
    float* p = sGL + row * 17 + t * 8;
    float mx = -3e38f;
#pragma unroll
    for (int e = 0; e < 8; ++e) mx = fmaxf(mx, p[e]);
    float sum = 0.f; float pe[8];
#pragma unroll
    for (int e = 0; e < 8; ++e) { pe[e] = __expf(p[e] - mx); sum += pe[e]; }
    float inv = 1.f / sum;
#pragma unroll
    for (int e = 0; e < 8; ++e) p[e] = pe[e] * inv;
  }
  __syncthreads();

  {
    int row = tid >> 3, q = tid & 7, t = q >> 2, o0 = (q & 3) * 32;
    const float* gp = sGL + row * 17 + t * 8;
    float accL[16], accH[16];
#pragma unroll
    for (int j = 0; j < 16; ++j) { accL[j] = 0.f; accH[j] = 0.f; }
    const unsigned short* base = eo_ws + ((size_t)(b0 + row) * 8) * 128 + o0;
#pragma unroll
    for (int e = 0; e < 8; ++e) {
      float ge = gp[e];
      const unsigned short* p = base + e * 128;
#pragma unroll
      for (int c = 0; c < 4; ++c) {
        uint4 v = *(const uint4*)(p + c * 8);
        const unsigned* u = (const unsigned*)&v;
#pragma unroll
        for (int j = 0; j < 4; ++j) {
          accL[c * 4 + j] += ge * bfLo(u[j]);
          accH[c * 4 + j] += ge * bfHi(u[j]);
        }
      }
    }
    unsigned short ob[32];
#pragma unroll
    for (int j = 0; j < 16; ++j) {
      ob[2 * j]     = f2bf(accL[j]);
      ob[2 * j + 1] = f2bf(accH[j]);
    }
#pragma unroll
    for (int c = 0; c < 4; ++c)
      *(uint4*)(sTi + t * 4096 + row * 128 + SWZ(row, o0 + c * 8)) = *(const uint4*)(ob + c * 8);
  }
  __syncthreads();

  int t = w >> 1, mt = w & 1;
  {
    f32x4 acc[4] = {{0.f,0.f,0.f,0.f},{0.f,0.f,0.f,0.f},{0.f,0.f,0.f,0.f},{0.f,0.f,0.f,0.f}};
    int ml = mt * 16 + lr;
#pragma unroll
    for (int kk = 0; kk < 4; ++kk) {
      bfrag a = *(const bfrag*)(sTi + t * 4096 + ml * 128 + SWZ(ml, kk * 32 + g * 8));
#pragma unroll
      for (int nt = 0; nt < 4; ++nt) {
        bfrag bb = *(const bfrag*)(tW1b + t * 8192 + (nt * 16 + lr) * 128 + kk * 32 + g * 8);
        acc[nt] = __builtin_amdgcn_mfma_f32_16x16x32_bf16(a, bb, acc[nt], 0, 0, 0);
      }
    }
#pragma unroll
    for (int nt = 0; nt < 4; ++nt) {
      int n = nt * 16 + lr;
      float bias = tb1[t * 64 + n];
#pragma unroll
      for (int r = 0; r < 4; ++r) {
        float x = fmaxf(acc[nt][r] + bias, 0.f);
        int row = mt * 16 + g * 4 + r;
        sX1[t * 2048 + row * 64 + SWZ(row, n)] = f2bf(x);
      }
    }
  }
  __syncthreads();

  {
    f32x4 acc[2] = {{0.f,0.f,0.f,0.f},{0.f,0.f,0.f,0.f}};
    int ml = mt * 16 + lr;
#pragma unroll
    for (int kk = 0; kk < 2; ++kk) {
      bfrag a = *(const bfrag*)(sX1 + t * 2048 + ml * 64 + SWZ(ml, kk * 32 + g * 8));
#pragma unroll
      for (int nt = 0; nt < 2; ++nt) {
        bfrag bb = *(const bfrag*)(tW2b + t * 2048 + (nt * 16 + lr) * 64 + kk * 32 + g * 8);
        acc[nt] = __builtin_amdgcn_mfma_f32_16x16x32_bf16(a, bb, acc[nt], 0, 0, 0);
      }
    }
    float part[4] = {0.f, 0.f, 0.f, 0.f};
#pragma unroll
    for (int nt = 0; nt < 2; ++nt) {
      int n = nt * 16 + lr;
      float bias = tb2[t * 32 + n];
      float w3 = tW3[t * 32 + n];
#pragma unroll
      for (int r = 0; r < 4; ++r)
        part[r] += fmaxf(acc[nt][r] + bias, 0.f) * w3;
    }
#pragma unroll
    for (int d = 1; d < 16; d <<= 1)
#pragma unroll
      for (int r = 0; r < 4; ++r) part[r] += __shfl_xor(part[r], d);
    if (lr == 0) {
      float b3 = tb3[t];
#pragma unroll
      for (int r = 0; r < 4; ++r) {
        float logit = part[r] + b3;
        out[(size_t)t * 16384 + b0 + mt * 16 + g * 4 + r] = 1.f / (1.f + __expf(-logit));
      }
    }
  }
}

// ---------------- launcher ----------------
extern "C" void kernel_launch(void* const* d_in, const int* in_sizes, int n_in,
                              void* d_out, int out_size, void* d_ws, size_t ws_size,
                              hipStream_t stream) {
  const int*   user_id    = (const int*)  d_in[0];
  const int*   item_id    = (const int*)  d_in[1];
  const int*   item_cat   = (const int*)  d_in[2];
  const int*   item_dur   = (const int*)  d_in[3];
  const float* user_dense = (const float*)d_in[4];
  const float* item_dense = (const float*)d_in[5];
  const int*   hist_seq   = (const int*)  d_in[6];
  const float* user_E     = (const float*)d_in[7];
  const float* item_E     = (const float*)d_in[8];
  const float* cat_E      = (const float*)d_in[9];
  const float* dur_E      = (const float*)d_in[10];
  const float* hist_E     = (const float*)d_in[11];
  const float* Wproj      = (const float*)d_in[12];
  const float* aW1        = (const float*)d_in[13];
  const float* ab1        = (const float*)d_in[14];
  const float* aW2        = (const float*)d_in[15];
  const float* ab2        = (const float*)d_in[16];
  const float* aW3        = (const float*)d_in[17];
  // d_in[18] = ab3: cancels in softmax, unused
  const float* eW1        = (const float*)d_in[19];
  const float* eb1        = (const float*)d_in[20];
  const float* eW2        = (const float*)d_in[21];
  const float* eb2        = (const float*)d_in[22];
  const float* gW         = (const float*)d_in[23];
  const float* gb         = (const float*)d_in[24];
  const float* tW1        = (const float*)d_in[25];
  const float* tb1        = (const float*)d_in[26];
  const float* tW2        = (const float*)d_in[27];
  const float* tb2        = (const float*)d_in[28];
  const float* tW3        = (const float*)d_in[29];
  const float* tb3        = (const float*)d_in[30];
  float* out = (float*)d_out;
  char* ws = (char*)d_ws;

  unsigned short* attnBt  = (unsigned short*)(ws + WS_ATTNB);
  unsigned short* aW2t    = (unsigned short*)(ws + WS_AW2T);
  unsigned short* eW1t    = (unsigned short*)(ws + WS_EW1T);
  unsigned short* eW2t    = (unsigned short*)(ws + WS_EW2T);
  unsigned short* hist_b  = (unsigned short*)(ws + WS_HISTB);
  unsigned short* tgt     = (unsigned short*)(ws + WS_TGT);
  float*          tA      = (float*)         (ws + WS_TA);
  unsigned short* shared_p= (unsigned short*)(ws + WS_SHP);
  unsigned short* eo_ws   = (unsigned short*)(ws + WS_EO);
  unsigned short* gWb     = (unsigned short*)(ws + WS_GWB);
  unsigned short* tW1b    = (unsigned short*)(ws + WS_TW1B);
  unsigned short* tW2b    = (unsigned short*)(ws + WS_TW2B);
  unsigned short* Wpb     = (unsigned short*)(ws + WS_WPB);
  unsigned short* WAb     = (unsigned short*)(ws + WS_WAB);

  k0_prep<<<2048, 256, 0, stream>>>(aW1, aW2, eW1, eW2, hist_E, gW, tW1, tW2, Wproj,
                                    attnBt, aW2t, eW1t, eW2t, hist_b,
                                    gWb, tW1b, tW2b, Wpb, WAb);
  k1_tgt<<<256, 256, 0, stream>>>(item_id, item_E, Wpb, WAb, ab1, tgt, tA);
  k3a_assemble<<<4096, 256, 0, stream>>>(user_id, item_id, item_cat, item_dur,
                                         user_dense, item_dense, user_E, item_E,
                                         cat_E, dur_E, shared_p);
  k2_attn<<<16384, 256, 0, stream>>>(hist_seq, hist_b, tgt, tA, attnBt, aW2t,
                                     ab2, aW3, shared_p);
  k3b_experts<<<2048, 256, 0, stream>>>(shared_p, eW1t, eW2t, eb1, eb2, eo_ws);
  k4_tail<<<512, 256, 0, stream>>>(shared_p, eo_ws, gWb, gb, tW1b, tb1, tW2b, tb2,
                                   tW3, tb3, out);
}

// Round 13
// 235.228 us; speedup vs baseline: 1.4253x; 1.0339x over previous
//
#include <hip/hip_runtime.h>
#include <hip/hip_bf16.h>
#include <cstdint>
#include <cmath>

// MMoE forward, MI355X. B=16384 L=200 SD=64 CONCAT=244 NE=8 EH=256 EO=128 NT=2.
// R3: M-fold. R4: MFMA k4. R6: HW cvt. R7: MFMA k1. R8: swapped-MFMA k2.
// R10: 5 blocks/CU L2 sweet spot (k2=147us). R11 lesson: conditionally-defined
// per-lane arrays spill. R13: register pooling redone spill-proof — unconditional
// h-frag loads (ids padded to 256), wave-uniform guards on MFMA/stores only,
// sSc[256] so pooling weights need no guard, launch_bounds(256,4) for VGPR<=128.

typedef __attribute__((ext_vector_type(8))) short bfrag;   // 8 x bf16 (A/B frag)
typedef __attribute__((ext_vector_type(4))) float f32x4;   // C/D frag

__device__ __forceinline__ unsigned short f2bf(float f) {
  __hip_bfloat16 h = __float2bfloat16(f);          // HW v_cvt on gfx950 (RNE)
  return __builtin_bit_cast(unsigned short, h);
}
__device__ __forceinline__ float bf2f(unsigned short b) {
  union { unsigned u; float f; } v; v.u = ((unsigned)b) << 16;
  return v.f;
}
__device__ __forceinline__ float bfLo(unsigned hv) {
  union { unsigned u; float f; } v; v.u = hv << 16;
  return v.f;
}
__device__ __forceinline__ float bfHi(unsigned hv) {
  union { unsigned u; float f; } v; v.u = hv & 0xffff0000u;
  return v.f;
}

#define SWZ(row, col) ((col) ^ (((row) & 7) << 3))   // element-unit XOR swizzle (16B units)

// ---------------- workspace layout (bytes) ----------------
static constexpr size_t WS_ATTNB = 0;                       // bf16 [64][128]  (n-major)
static constexpr size_t WS_AW2T  = WS_ATTNB + 16384;        // bf16 [16][64]
static constexpr size_t WS_A13   = WS_AW2T + 2048;          // (unused gap)
static constexpr size_t WS_EW1T  = WS_A13 + 16384;          // bf16 [8][256][256]
static constexpr size_t WS_EW2T  = WS_EW1T + 1048576;       // bf16 [8][128][256]
static constexpr size_t WS_HISTB = WS_EW2T + 524288;        // bf16 [100001][64]
static constexpr size_t WS_TGT   = WS_HISTB + 12800256;     // bf16 [B][64]
static constexpr size_t WS_TA    = WS_TGT + 2097152;        // f32  [B][64]
static constexpr size_t WS_SHP   = WS_TA + 4194304;         // bf16 [B][256]
static constexpr size_t WS_EO    = WS_SHP + 8388608;        // bf16 [B][8][128]
static constexpr size_t WS_GWB   = WS_EO + 33554432;        // bf16 [16][256]
static constexpr size_t WS_TW1B  = WS_GWB + 8192;           // bf16 [2][64][128]
static constexpr size_t WS_TW2B  = WS_TW1B + 32768;         // bf16 [2][32][64]
static constexpr size_t WS_WPB   = WS_TW2B + 8192;          // bf16 [64][64]  Wproj^T (n-major)
static constexpr size_t WS_WAB   = WS_WPB + 8192;           // bf16 [64][64]  (Wproj@A13)^T
// total = WS_WAB + 8192 = 62,707,712 bytes of d_ws

// ---------------- k0: fold/transpose/bf16-cast weights + hist table ----------------
__launch_bounds__(256)
__global__ void k0_prep(const float* __restrict__ aW1, const float* __restrict__ aW2,
                        const float* __restrict__ eW1, const float* __restrict__ eW2,
                        const float* __restrict__ hist_E,
                        const float* __restrict__ gW, const float* __restrict__ tW1,
                        const float* __restrict__ tW2, const float* __restrict__ Wproj,
                        unsigned short* __restrict__ attnBt, unsigned short* __restrict__ aW2t,
                        unsigned short* __restrict__ eW1t, unsigned short* __restrict__ eW2t,
                        unsigned short* __restrict__ hist_b,
                        unsigned short* __restrict__ gWb, unsigned short* __restrict__ tW1b,
                        unsigned short* __restrict__ tW2b,
                        unsigned short* __restrict__ Wpb, unsigned short* __restrict__ WAb) {
  int tid = blockIdx.x * blockDim.x + threadIdx.x;
  int nth = gridDim.x * blockDim.x;
  // attnBt[n][k]: k<64 -> A2-A3, k>=64 -> A4
  for (int i = tid; i < 64 * 128; i += nth) {
    int n = i >> 7, k = i & 127;
    float v = (k < 64) ? (aW1[(64 + k) * 64 + n] - aW1[(128 + k) * 64 + n])
                       : aW1[(128 + k) * 64 + n];
    attnBt[i] = f2bf(v);
  }
  // aW2t[n][k]
  for (int i = tid; i < 16 * 64; i += nth) {
    int n = i >> 6, k = i & 63;
    aW2t[i] = f2bf(aW2[k * 16 + n]);
  }
  // Wpb[n][k] = Wproj[k][n]
  for (int i = tid; i < 64 * 64; i += nth) {
    int n = i >> 6, k = i & 63;
    Wpb[i] = f2bf(Wproj[k * 64 + n]);
  }
  // WAb[n][k] = sum_j Wproj[k][j]*(A1+A3)[j][n]
  for (int i = tid; i < 64 * 64; i += nth) {
    int n = i >> 6, k = i & 63;
    float s = 0.f;
    for (int j = 0; j < 64; ++j)
      s += Wproj[k * 64 + j] * (aW1[j * 64 + n] + aW1[(128 + j) * 64 + n]);
    WAb[i] = f2bf(s);
  }
  // eW1t[e][n][k]
  for (int i = tid; i < 8 * 256 * 256; i += nth) {
    int e = i >> 16, n = (i >> 8) & 255, k = i & 255;
    eW1t[i] = (k < 244) ? f2bf(eW1[(e * 244 + k) * 256 + n]) : (unsigned short)0;
  }
  // eW2t[e][n][k]
  for (int i = tid; i < 8 * 128 * 256; i += nth) {
    int e = i >> 15, n = (i >> 8) & 127, k = i & 255;
    eW2t[i] = f2bf(eW2[(e * 256 + k) * 128 + n]);
  }
  // gWb[n][k]
  for (int i = tid; i < 16 * 256; i += nth) {
    int n = i >> 8, k = i & 255, t = n >> 3, e = n & 7;
    gWb[i] = (k < 244) ? f2bf(gW[(t * 244 + k) * 8 + e]) : (unsigned short)0;
  }
  // tW1b[t][n][k]
  for (int i = tid; i < 2 * 64 * 128; i += nth) {
    int t = i >> 13, n = (i >> 7) & 63, k = i & 127;
    tW1b[i] = f2bf(tW1[(t * 128 + k) * 64 + n]);
  }
  // tW2b[t][n][k]
  for (int i = tid; i < 2 * 32 * 64; i += nth) {
    int t = i >> 11, n = (i >> 6) & 31, k = i & 63;
    tW2b[i] = f2bf(tW2[(t * 64 + k) * 32 + n]);
  }
  // bf16 hist table, vectorized 8-wide (6,400,064 = 800,008 * 8 exactly)
  for (int i = tid; i < 800008; i += nth) {
    const float* src = hist_E + (size_t)i * 8;
    float4 a = *(const float4*)src;
    float4 c = *(const float4*)(src + 4);
    uint4 q;
    q.x = (unsigned)f2bf(a.x) | ((unsigned)f2bf(a.y) << 16);
    q.y = (unsigned)f2bf(a.z) | ((unsigned)f2bf(a.w) << 16);
    q.z = (unsigned)f2bf(c.x) | ((unsigned)f2bf(c.y) << 16);
    q.w = (unsigned)f2bf(c.z) | ((unsigned)f2bf(c.w) << 16);
    *(uint4*)(hist_b + (size_t)i * 8) = q;
  }
}

// ---------------- k1: t = i_emb@Wproj ; tA = i_emb@WA + ab1  (MFMA) ----------------
__launch_bounds__(256)
__global__ void k1_tgt(const int* __restrict__ item_id, const float* __restrict__ item_E,
                       const unsigned short* __restrict__ Wpb, const unsigned short* __restrict__ WAb,
                       const float* __restrict__ ab1,
                       unsigned short* __restrict__ tgt, float* __restrict__ tA) {
  int tid = threadIdx.x, w = tid >> 6, lane = tid & 63;
  int lr = lane & 15, g = lane >> 4;
  int b0 = blockIdx.x * 64 + w * 16;
  int iid = item_id[b0 + lr];
  bfrag ia[2];
#pragma unroll
  for (int kk = 0; kk < 2; ++kk) {
    const float* src = item_E + (size_t)iid * 64 + kk * 32 + g * 8;
    float4 x = *(const float4*)src;
    float4 y = *(const float4*)(src + 4);
    bfrag r;
    r[0] = (short)f2bf(x.x); r[1] = (short)f2bf(x.y);
    r[2] = (short)f2bf(x.z); r[3] = (short)f2bf(x.w);
    r[4] = (short)f2bf(y.x); r[5] = (short)f2bf(y.y);
    r[6] = (short)f2bf(y.z); r[7] = (short)f2bf(y.w);
    ia[kk] = r;
  }
  f32x4 at[4], aa[4];
#pragma unroll
  for (int i = 0; i < 4; ++i) { at[i] = (f32x4){0,0,0,0}; aa[i] = (f32x4){0,0,0,0}; }
#pragma unroll
  for (int kk = 0; kk < 2; ++kk)
#pragma unroll
    for (int nt = 0; nt < 4; ++nt) {
      bfrag wp = *(const bfrag*)(Wpb + (nt * 16 + lr) * 64 + kk * 32 + g * 8);
      at[nt] = __builtin_amdgcn_mfma_f32_16x16x32_bf16(ia[kk], wp, at[nt], 0, 0, 0);
      bfrag wa = *(const bfrag*)(WAb + (nt * 16 + lr) * 64 + kk * 32 + g * 8);
      aa[nt] = __builtin_amdgcn_mfma_f32_16x16x32_bf16(ia[kk], wa, aa[nt], 0, 0, 0);
    }
  // D: col n = nt*16+lr, row m = b0 + g*4 + r
#pragma unroll
  for (int nt = 0; nt < 4; ++nt) {
    int n = nt * 16 + lr;
    float b1 = ab1[n];
#pragma unroll
    for (int r = 0; r < 4; ++r) {
      int m = b0 + g * 4 + r;
      tgt[(size_t)m * 64 + n] = f2bf(at[nt][r]);
      tA[(size_t)m * 64 + n] = aa[nt][r] + b1;
    }
  }
}

// ---------------- k3a: assemble shared (cols 0..179, pad 244..255) ----------------
__launch_bounds__(256)
__global__ void k3a_assemble(const int* __restrict__ user_id, const int* __restrict__ item_id,
                             const int* __restrict__ item_cat, const int* __restrict__ item_dur,
                             const float* __restrict__ user_dense, const float* __restrict__ item_dense,
                             const float* __restrict__ user_E, const float* __restrict__ item_E,
                             const float* __restrict__ cat_E, const float* __restrict__ dur_E,
                             unsigned short* __restrict__ shared_p) {
  int tid = threadIdx.x, w = tid >> 6, lane = tid & 63;
  int b = blockIdx.x * 4 + w;
  unsigned short* row = shared_p + (size_t)b * 256;
  row[lane]      = f2bf(user_E[(size_t)user_id[b] * 64 + lane]);
  row[64 + lane] = f2bf(item_E[(size_t)item_id[b] * 64 + lane]);
  if (lane < 16) row[128 + lane] = f2bf(cat_E[item_cat[b] * 16 + lane]);
  if (lane < 8)  row[144 + lane] = f2bf(dur_E[item_dur[b] * 8 + lane]);
  if (lane < 25) row[152 + lane] = f2bf(user_dense[b * 25 + lane]);
  if (lane < 3)  row[177 + lane] = f2bf(item_dense[b * 3 + lane]);
  if (lane < 12) row[244 + lane] = 0;
}

// ---------------- k2: fused DIN attention (reg pooling, spill-proof) ---------------
__launch_bounds__(256, 4)
__global__ void k2_attn(const int* __restrict__ hist_seq, const unsigned short* __restrict__ hist_b,
                        const unsigned short* __restrict__ tgt, const float* __restrict__ tA,
                        const unsigned short* __restrict__ attnBt_g, const unsigned short* __restrict__ aW2t_g,
                        const float* __restrict__ ab2, const float* __restrict__ aW3,
                        unsigned short* __restrict__ shared_p) {
  __shared__ unsigned short sH1[208 * 64];   // L1 out (swizzled); transiently M, later f32[256][17] partials
  __shared__ int   ids[256];
  __shared__ float tv[64], tAv[64];
  __shared__ float sSc[256];
  __shared__ float red[8];
  int b = blockIdx.x;
  int tid = threadIdx.x, w = tid >> 6, lane = tid & 63;
  int lr = lane & 15, g = lane >> 4;

  ids[tid] = (tid < 200) ? hist_seq[(size_t)b * 200 + tid] : 0;
  if (tid < 64) tv[tid] = bf2f(tgt[(size_t)b * 64 + tid]);
  else if (tid < 128) tAv[tid - 64] = tA[(size_t)b * 64 + (tid - 64)];

  // layer-2 A fragments (aW2t rows n2=lr) + per-lane ab2/aW3 (n2 = g*4+r)
  bfrag b2fr[2];
#pragma unroll
  for (int kk = 0; kk < 2; ++kk)
    b2fr[kk] = *(const bfrag*)(aW2t_g + lr * 64 + kk * 32 + g * 8);
  f32x4 ab2v4 = *(const f32x4*)(ab2 + g * 4);
  f32x4 aW3v4 = *(const f32x4*)(aW3 + g * 4);
  __syncthreads();   // tv ready

  // cooperative M[n][k] = A23[n][k] + t[k]*A4[n][k] into sH1[0:4096] (swizzled)
  {
    int n = tid >> 2, k0 = (tid & 3) * 16;
    const unsigned short* rowp = attnBt_g + n * 128;
    unsigned short a23[16], a4[16], mo[16];
    *(uint4*)(a23)     = *(const uint4*)(rowp + k0);
    *(uint4*)(a23 + 8) = *(const uint4*)(rowp + k0 + 8);
    *(uint4*)(a4)      = *(const uint4*)(rowp + 64 + k0);
    *(uint4*)(a4 + 8)  = *(const uint4*)(rowp + 64 + k0 + 8);
#pragma unroll
    for (int i = 0; i < 16; ++i)
      mo[i] = f2bf(bf2f(a23[i]) + tv[k0 + i] * bf2f(a4[i]));
    *(uint4*)(sH1 + n * 64 + SWZ(n, k0))     = *(uint4*)(mo);
    *(uint4*)(sH1 + n * 64 + SWZ(n, k0 + 8)) = *(uint4*)(mo + 8);
  }
  __syncthreads();   // M ready

  // hoist M A-fragments (rows n1 = nt*16+lr) into registers
  bfrag mfr[4][2];
#pragma unroll
  for (int nt = 0; nt < 4; ++nt)
#pragma unroll
    for (int kk = 0; kk < 2; ++kk) {
      int n = nt * 16 + lr;
      mfr[nt][kk] = *(const bfrag*)(sH1 + n * 64 + SWZ(n, kk * 32 + g * 8));
    }
  __syncthreads();   // all waves have M; sH1 free for L1 output

  // layer 1 (swapped): 4 unconditional slots; h-frags stay live for pooling.
  // MFMA + LDS write guarded by WAVE-UNIFORM (mt<13); loads always execute
  // (rows >=208 use ids=0 -> hist padding row 0).
  bfrag h0s[4], h1s[4];
#pragma unroll
  for (int s = 0; s < 4; ++s) {
    int mt = w + 4 * s;
    int m = mt * 16 + lr;
    const unsigned short* hrow = hist_b + (size_t)ids[m] * 64;
    h0s[s] = *(const bfrag*)(hrow + g * 8);
    h1s[s] = *(const bfrag*)(hrow + 32 + g * 8);
    if (mt < 13) {
      f32x4 acc[4] = {{0,0,0,0},{0,0,0,0},{0,0,0,0},{0,0,0,0}};
#pragma unroll
      for (int nt = 0; nt < 4; ++nt) {
        acc[nt] = __builtin_amdgcn_mfma_f32_16x16x32_bf16(mfr[nt][0], h0s[s], acc[nt], 0, 0, 0);
        acc[nt] = __builtin_amdgcn_mfma_f32_16x16x32_bf16(mfr[nt][1], h1s[s], acc[nt], 0, 0, 0);
      }
#pragma unroll
      for (int nt = 0; nt < 4; ++nt) {
        f32x4 ta4 = *(const f32x4*)(tAv + nt * 16 + g * 4);
        unsigned lo = (unsigned)f2bf(fmaxf(acc[nt][0] + ta4[0], 0.f))
                    | ((unsigned)f2bf(fmaxf(acc[nt][1] + ta4[1], 0.f)) << 16);
        unsigned hi = (unsigned)f2bf(fmaxf(acc[nt][2] + ta4[2], 0.f))
                    | ((unsigned)f2bf(fmaxf(acc[nt][3] + ta4[3], 0.f)) << 16);
        uint2 pk; pk.x = lo; pk.y = hi;
        *(uint2*)(sH1 + m * 64 + SWZ(m, nt * 16 + g * 4)) = pk;
      }
    }
  }
  __syncthreads();

  // layer 2 (swapped): D2[n2][m]; 2-shuffle score reduce (wave-uniform guard)
#pragma unroll
  for (int s = 0; s < 4; ++s) {
    int mt = w + 4 * s;
    if (mt < 13) {
      int m = mt * 16 + lr;
      f32x4 acc2 = {0.f, 0.f, 0.f, 0.f};
#pragma unroll
      for (int kk = 0; kk < 2; ++kk) {
        bfrag hb = *(const bfrag*)(sH1 + m * 64 + SWZ(m, kk * 32 + g * 8));
        acc2 = __builtin_amdgcn_mfma_f32_16x16x32_bf16(b2fr[kk], hb, acc2, 0, 0, 0);
      }
      float p = 0.f;
#pragma unroll
      for (int r = 0; r < 4; ++r)
        p += fmaxf(acc2[r] + ab2v4[r], 0.f) * aW3v4[r];
      p += __shfl_xor(p, 16);
      p += __shfl_xor(p, 32);
      if (lane < 16) sSc[m] = p;
    }
  }
  __syncthreads();

  // masked softmax; ALL 256 threads write p (0 for invalid / padded rows)
  bool valid = false; float sc0 = 0.f;
  if (tid < 200 && ids[tid] != 0) { valid = true; sc0 = sSc[tid]; }
  float v = valid ? sc0 : -3.0e38f;
#pragma unroll
  for (int d = 1; d < 64; d <<= 1) v = fmaxf(v, __shfl_xor(v, d));
  if (lane == 0) red[w] = v;
  __syncthreads();
  float mx = fmaxf(fmaxf(red[0], red[1]), fmaxf(red[2], red[3]));
  float p = valid ? __expf(sc0 - mx) : 0.f;
  float s = p;
#pragma unroll
  for (int d = 1; d < 64; d <<= 1) s += __shfl_xor(s, d);
  if (lane == 0) red[4 + w] = s;
  sSc[tid] = p;
  __syncthreads();   // p ready; all sH1 reads done

  // pooled: accumulate from register-held h (no re-gather; padded rows weight 0)
  {
    float pacc[16];
#pragma unroll
    for (int i = 0; i < 16; ++i) pacc[i] = 0.f;
#pragma unroll
    for (int s2 = 0; s2 < 4; ++s2) {
      int m = (w + 4 * s2) * 16 + lr;
      float pm = sSc[m];
#pragma unroll
      for (int i = 0; i < 8; ++i) {
        pacc[i]     += pm * bf2f((unsigned short)h0s[s2][i]);
        pacc[8 + i] += pm * bf2f((unsigned short)h1s[s2][i]);
      }
    }
    float* sf = (float*)sH1;   // f32[256][17], stride 17 -> <=2-way banks
#pragma unroll
    for (int i = 0; i < 16; ++i) sf[tid * 17 + i] = pacc[i];
  }
  __syncthreads();
  // stage 2: 256 threads each reduce 16 partials for (ww, output d)
  {
    int d = tid & 63, ww = tid >> 6;
    int gg = (d & 31) >> 3, ii = (d & 7) + ((d >> 5) << 3);
    const float* sf = (const float*)sH1;
    float part = 0.f;
#pragma unroll
    for (int l2 = 0; l2 < 16; ++l2)
      part += sf[(ww * 64 + gg * 16 + l2) * 17 + ii];
    sSc[tid] = part;
  }
  __syncthreads();
  if (tid < 64) {
    float denom = red[4] + red[5] + red[6] + red[7] + 1e-30f;
    float tot = sSc[tid] + sSc[64 + tid] + sSc[128 + tid] + sSc[192 + tid];
    shared_p[(size_t)b * 256 + 180 + tid] = f2bf(tot / denom);
  }
}

// ---------------- k3b: experts (64-row tile x one expert per block) ----------------
__launch_bounds__(256, 2)
__global__ void k3b_experts(const unsigned short* __restrict__ shared_p,
                            const unsigned short* __restrict__ eW1t, const unsigned short* __restrict__ eW2t,
                            const float* __restrict__ eb1, const float* __restrict__ eb2,
                            unsigned short* __restrict__ eo_ws) {
  __shared__ unsigned short sX[64 * 256];
  __shared__ unsigned short sW[256 * 64];
  int tid = threadIdx.x, w = tid >> 6, lane = tid & 63;
  int e = blockIdx.x & 7;
  int b0 = (blockIdx.x >> 3) * 64;
  int lr = lane & 15, g = lane >> 4;

  for (int j = tid; j < 2048; j += 256) {
    int r = j >> 5, ke = (j & 31) * 8;
    uint4 v = *(const uint4*)(shared_p + (size_t)(b0 + r) * 256 + ke);
    *(uint4*)(sX + r * 256 + SWZ(r, ke)) = v;
  }
  f32x4 acc[16];
#pragma unroll
  for (int i = 0; i < 16; ++i) acc[i] = (f32x4){0.f, 0.f, 0.f, 0.f};
  const unsigned short* w1 = eW1t + (size_t)e * 256 * 256;
  for (int c = 0; c < 4; ++c) {
    __syncthreads();
    for (int j = tid; j < 2048; j += 256) {
      int n = j >> 3, ke = (j & 7) * 8;
      uint4 v = *(const uint4*)(w1 + n * 256 + c * 64 + ke);
      *(uint4*)(sW + n * 64 + SWZ(n, ke)) = v;
    }
    __syncthreads();
    int m = w * 16 + lr;
#pragma unroll
    for (int kk = 0; kk < 2; ++kk) {
      int kabs = c * 64 + kk * 32 + g * 8;
      bfrag a = *(const bfrag*)(sX + m * 256 + SWZ(m, kabs));
      int kloc = kk * 32 + g * 8;
#pragma unroll
      for (int nt = 0; nt < 16; ++nt) {
        int n = nt * 16 + lr;
        bfrag bb = *(const bfrag*)(sW + n * 64 + SWZ(n, kloc));
        acc[nt] = __builtin_amdgcn_mfma_f32_16x16x32_bf16(a, bb, acc[nt], 0, 0, 0);
      }
    }
  }
  __syncthreads();
#pragma unroll
  for (int nt = 0; nt < 16; ++nt) {
    int n = nt * 16 + lr;
    float bb = eb1[e * 256 + n];
#pragma unroll
    for (int r = 0; r < 4; ++r) {
      float vv = fmaxf(acc[nt][r] + bb, 0.f);
      int mm = w * 16 + g * 4 + r;
      sX[mm * 256 + SWZ(mm, n)] = f2bf(vv);
    }
  }
  f32x4 acc2[8];
#pragma unroll
  for (int i = 0; i < 8; ++i) acc2[i] = (f32x4){0.f, 0.f, 0.f, 0.f};
  const unsigned short* w2 = eW2t + (size_t)e * 128 * 256;
  for (int c = 0; c < 4; ++c) {
    __syncthreads();
    for (int j = tid; j < 1024; j += 256) {
      int n = j >> 3, ke = (j & 7) * 8;
      uint4 v = *(const uint4*)(w2 + n * 256 + c * 64 + ke);
      *(uint4*)(sW + n * 64 + SWZ(n, ke)) = v;
    }
    __syncthreads();
    int m = w * 16 + lr;
#pragma unroll
    for (int kk = 0; kk < 2; ++kk) {
      int kabs = c * 64 + kk * 32 + g * 8;
      bfrag a = *(const bfrag*)(sX + m * 256 + SWZ(m, kabs));
      int kloc = kk * 32 + g * 8;
#pragma unroll
      for (int nt = 0; nt < 8; ++nt) {
        int n = nt * 16 + lr;
        bfrag bb = *(const bfrag*)(sW + n * 64 + SWZ(n, kloc));
        acc2[nt] = __builtin_amdgcn_mfma_f32_16x16x32_bf16(a, bb, acc2[nt], 0, 0, 0);
      }
    }
  }
#pragma unroll
  for (int nt = 0; nt < 8; ++nt) {
    int n = nt * 16 + lr;
    float bb = eb2[e * 128 + n];
#pragma unroll
    for (int r = 0; r < 4; ++r) {
      float vv = fmaxf(acc2[nt][r] + bb, 0.f);
      int mm = w * 16 + g * 4 + r;
      eo_ws[((size_t)(b0 + mm) * 8 + e) * 128 + n] = f2bf(vv);
    }
  }
}

// ---------------- k4: gates + mixture + towers + sigmoid (MFMA tail) ----------------
__launch_bounds__(256, 3)
__global__ void k4_tail(const unsigned short* __restrict__ shared_p, const unsigned short* __restrict__ eo_ws,
                        const unsigned short* __restrict__ gWb, const float* __restrict__ gb,
                        const unsigned short* __restrict__ tW1b, const float* __restrict__ tb1,
                        const unsigned short* __restrict__ tW2b, const float* __restrict__ tb2,
                        const float* __restrict__ tW3, const float* __restrict__ tb3,
                        float* __restrict__ out) {
  __shared__ float sGL[32 * 17];
  __shared__ unsigned short sTi[2 * 32 * 128];
  __shared__ unsigned short sX1[2 * 32 * 64];
  int tid = threadIdx.x, w = tid >> 6, lane = tid & 63;
  int lr = lane & 15, g = lane >> 4;
  int b0 = blockIdx.x * 32;

  if (w < 2) {
    int m = b0 + w * 16 + lr;
    f32x4 acc = {0.f, 0.f, 0.f, 0.f};
#pragma unroll
    for (int kk = 0; kk < 8; ++kk) {
      bfrag a = *(const bfrag*)(shared_p + (size_t)m * 256 + kk * 32 + g * 8);
      bfrag bb = *(const bfrag*)(gWb + lr * 256 + kk * 32 + g * 8);
      acc = __builtin_amdgcn_mfma_f32_16x16x32_bf16(a, bb, acc, 0, 0, 0);
    }
    float gbv = gb[lr];
#pragma unroll
    for (int r = 0; r < 4; ++r)
      sGL[(w * 16 + g * 4 + r) * 17 + lr] = acc[r] + gbv;
  }
  __syncthreads();

  if (tid < 64) {
    int row = tid >> 1, t = tid & 1;
    float* p = sGL + row * 17 + t * 8;
    float mx = -3e38f;
#pragma unroll
    for (int e = 0; e < 8; ++e) mx = fmaxf(mx, p[e]);
    float sum = 0.f; float pe[8];
#pragma unroll
    for (int e = 0; e < 8; ++e) { pe[e] = __expf(p[e] - mx); sum += pe[e]; }
    float inv = 1.f / sum;
#pragma unroll
    for (int e = 0; e < 8; ++e) p[e] = pe[e] * inv;
  }
  __syncthreads();

  {
    int row = tid >> 3, q = tid & 7, t = q >> 2, o0 = (q & 3) * 32;
    const float* gp = sGL + row * 17 + t * 8;
    float accL[16], accH[16];
#pragma unroll
    for (int j = 0; j < 16; ++j) { accL[j] = 0.f; accH[j] = 0.f; }
    const unsigned short* base = eo_ws + ((size_t)(b0 + row) * 8) * 128 + o0;
#pragma unroll
    for (int e = 0; e < 8; ++e) {
      float ge = gp[e];
      const unsigned short* p = base + e * 128;
#pragma unroll
      for (int c = 0; c < 4; ++c) {
        uint4 v = *(const uint4*)(p + c * 8);
        const unsigned* u = (const unsigned*)&v;
#pragma unroll
        for (int j = 0; j < 4; ++j) {
          accL[c * 4 + j] += ge * bfLo(u[j]);
          accH[c * 4 + j] += ge * bfHi(u[j]);
        }
      }
    }
    unsigned short ob[32];
#pragma unroll
    for (int j = 0; j < 16; ++j) {
      ob[2 * j]     = f2bf(accL[j]);
      ob[2 * j + 1] = f2bf(accH[j]);
    }
#pragma unroll
    for (int c = 0; c < 4; ++c)
      *(uint4*)(sTi + t * 4096 + row * 128 + SWZ(row, o0 + c * 8)) = *(const uint4*)(ob + c * 8);
  }
  __syncthreads();

  int t = w >> 1, mt = w & 1;
  {
    f32x4 acc[4] = {{0.f,0.f,0.f,0.f},{0.f,0.f,0.f,0.f},{0.f,0.f,0.f,0.f},{0.f,0.f,0.f,0.f}};
    int ml = mt * 16 + lr;
#pragma unroll
    for (int kk = 0; kk < 4; ++kk) {
      bfrag a = *(const bfrag*)(sTi + t * 4096 + ml * 128 + SWZ(ml, kk * 32 + g * 8));
#pragma unroll
      for (int nt = 0; nt < 4; ++nt) {
        bfrag bb = *(const bfrag*)(tW1b + t * 8192 + (nt * 16 + lr) * 128 + kk * 32 + g * 8);
        acc[nt] = __builtin_amdgcn_mfma_f32_16x16x32_bf16(a, bb, acc[nt], 0, 0, 0);
      }
    }
#pragma unroll
    for (int nt = 0; nt < 4; ++nt) {
      int n = nt * 16 + lr;
      float bias = tb1[t * 64 + n];
#pragma unroll
      for (int r = 0; r < 4; ++r) {
        float x = fmaxf(acc[nt][r] + bias, 0.f);
        int row = mt * 16 + g * 4 + r;
        sX1[t * 2048 + row * 64 + SWZ(row, n)] = f2bf(x);
      }
    }
  }
  __syncthreads();

  {
    f32x4 acc[2] = {{0.f,0.f,0.f,0.f},{0.f,0.f,0.f,0.f}};
    int ml = mt * 16 + lr;
#pragma unroll
    for (int kk = 0; kk < 2; ++kk) {
      bfrag a = *(const bfrag*)(sX1 + t * 2048 + ml * 64 + SWZ(ml, kk * 32 + g * 8));
#pragma unroll
      for (int nt = 0; nt < 2; ++nt) {
        bfrag bb = *(const bfrag*)(tW2b + t * 2048 + (nt * 16 + lr) * 64 + kk * 32 + g * 8);
        acc[nt] = __builtin_amdgcn_mfma_f32_16x16x32_bf16(a, bb, acc[nt], 0, 0, 0);
      }
    }
    float part[4] = {0.f, 0.f, 0.f, 0.f};
#pragma unroll
    for (int nt = 0; nt < 2; ++nt) {
      int n = nt * 16 + lr;
      float bias = tb2[t * 32 + n];
      float w3 = tW3[t * 32 + n];
#pragma unroll
      for (int r = 0; r < 4; ++r)
        part[r] += fmaxf(acc[nt][r] + bias, 0.f) * w3;
    }
#pragma unroll
    for (int d = 1; d < 16; d <<= 1)
#pragma unroll
      for (int r = 0; r < 4; ++r) part[r] += __shfl_xor(part[r], d);
    if (lr == 0) {
      float b3 = tb3[t];
#pragma unroll
      for (int r = 0; r < 4; ++r) {
        float logit = part[r] + b3;
        out[(size_t)t * 16384 + b0 + mt * 16 + g * 4 + r] = 1.f / (1.f + __expf(-logit));
      }
    }
  }
}

// ---------------- launcher ----------------
extern "C" void kernel_launch(void* const* d_in, const int* in_sizes, int n_in,
                              void* d_out, int out_size, void* d_ws, size_t ws_size,
                              hipStream_t stream) {
  const int*   user_id    = (const int*)  d_in[0];
  const int*   item_id    = (const int*)  d_in[1];
  const int*   item_cat   = (const int*)  d_in[2];
  const int*   item_dur   = (const int*)  d_in[3];
  const float* user_dense = (const float*)d_in[4];
  const float* item_dense = (const float*)d_in[5];
  const int*   hist_seq   = (const int*)  d_in[6];
  const float* user_E     = (const float*)d_in[7];
  const float* item_E     = (const float*)d_in[8];
  const float* cat_E      = (const float*)d_in[9];
  const float* dur_E      = (const float*)d_in[10];
  const float* hist_E     = (const float*)d_in[11];
  const float* Wproj      = (const float*)d_in[12];
  const float* aW1        = (const float*)d_in[13];
  const float* ab1        = (const float*)d_in[14];
  const float* aW2        = (const float*)d_in[15];
  const float* ab2        = (const float*)d_in[16];
  const float* aW3        = (const float*)d_in[17];
  // d_in[18] = ab3: cancels in softmax, unused
  const float* eW1        = (const float*)d_in[19];
  const float* eb1        = (const float*)d_in[20];
  const float* eW2        = (const float*)d_in[21];
  const float* eb2        = (const float*)d_in[22];
  const float* gW         = (const float*)d_in[23];
  const float* gb         = (const float*)d_in[24];
  const float* tW1        = (const float*)d_in[25];
  const float* tb1        = (const float*)d_in[26];
  const float* tW2        = (const float*)d_in[27];
  const float* tb2        = (const float*)d_in[28];
  const float* tW3        = (const float*)d_in[29];
  const float* tb3        = (const float*)d_in[30];
  float* out = (float*)d_out;
  char* ws = (char*)d_ws;

  unsigned short* attnBt  = (unsigned short*)(ws + WS_ATTNB);
  unsigned short* aW2t    = (unsigned short*)(ws + WS_AW2T);
  unsigned short* eW1t    = (unsigned short*)(ws + WS_EW1T);
  unsigned short* eW2t    = (unsigned short*)(ws + WS_EW2T);
  unsigned short* hist_b  = (unsigned short*)(ws + WS_HISTB);
  unsigned short* tgt     = (unsigned short*)(ws + WS_TGT);
  float*          tA      = (float*)         (ws + WS_TA);
  unsigned short* shared_p= (unsigned short*)(ws + WS_SHP);
  unsigned short* eo_ws   = (unsigned short*)(ws + WS_EO);
  unsigned short* gWb     = (unsigned short*)(ws + WS_GWB);
  unsigned short* tW1b    = (unsigned short*)(ws + WS_TW1B);
  unsigned short* tW2b    = (unsigned short*)(ws + WS_TW2B);
  unsigned short* Wpb     = (unsigned short*)(ws + WS_WPB);
  unsigned short* WAb     = (unsigned short*)(ws + WS_WAB);

  k0_prep<<<2048, 256, 0, stream>>>(aW1, aW2, eW1, eW2, hist_E, gW, tW1, tW2, Wproj,
                                    attnBt, aW2t, eW1t, eW2t, hist_b,
                                    gWb, tW1b, tW2b, Wpb, WAb);
  k1_tgt<<<256, 256, 0, stream>>>(item_id, item_E, Wpb, WAb, ab1, tgt, tA);
  k3a_assemble<<<4096, 256, 0, stream>>>(user_id, item_id, item_cat, item_dur,
                                         user_dense, item_dense, user_E, item_E,
                                         cat_E, dur_E, shared_p);
  k2_attn<<<16384, 256, 0, stream>>>(hist_seq, hist_b, tgt, tA, attnBt, aW2t,
                                     ab2, aW3, shared_p);
  k3b_experts<<<2048, 256, 0, stream>>>(shared_p, eW1t, eW2t, eb1, eb2, eo_ws);
  k4_tail<<<512, 256, 0, stream>>>(shared_p, eo_ws, gWb, gb, tW1b, tb1, tW2b, tb2,
                                   tW3, tb3, out);
}